// Round 2
// baseline (494.331 us; speedup 1.0000x reference)
//
#include <hip/hip_runtime.h>

#define HIDDEN 2048
#define SEQ    2048
#define BATCH  2
#define NHEAD  16
#define HDIM   128

typedef __attribute__((ext_vector_type(4))) int    i32x4;
typedef __attribute__((ext_vector_type(4))) float  f32x4;
typedef __attribute__((ext_vector_type(8))) __bf16 bf16x8;

__device__ __forceinline__ unsigned short f2bf(float f) {
    unsigned u = __builtin_bit_cast(unsigned, f);
    u += 0x7FFFu + ((u >> 16) & 1u);   // RNE (no NaN inputs in this pipeline)
    return (unsigned short)(u >> 16);
}
__device__ __forceinline__ float bf2f(unsigned short h) {
    unsigned u = ((unsigned)h) << 16;
    return __builtin_bit_cast(float, u);
}

// ---------------- RoPE tables: ctab/stab[t*64 + i] = cos/sin(t * 10000^(-i/64))
__global__ void k_rope_tables(float* __restrict__ ctab, float* __restrict__ stab) {
    int idx = blockIdx.x * 256 + threadIdx.x;      // exactly SEQ*64 threads
    int t = idx >> 6, i = idx & 63;
    float inv = expf(-(float)i * 0.14391156831212793f);  // ln(10000)/64
    float ang = (float)t * inv;
    ctab[idx] = cosf(ang);
    stab[idx] = sinf(ang);
}

// ---------------- fp32 -> bf16 convert (4 elems/thread)
__global__ void k_cvt_bf16(const float* __restrict__ in, unsigned short* __restrict__ out, int n4) {
    int idx = blockIdx.x * blockDim.x + threadIdx.x;
    if (idx < n4) {
        float4 v = ((const float4*)in)[idx];
        ushort4 o;
        o.x = f2bf(v.x); o.y = f2bf(v.y); o.z = f2bf(v.z); o.w = f2bf(v.w);
        ((ushort4*)out)[idx] = o;
    }
}

// ---------------- W (K x N fp32) -> W^T (N x K bf16), 32x32 LDS tiles
__global__ void k_transcvt(const float* __restrict__ in, unsigned short* __restrict__ out) {
    __shared__ float tile[32][33];
    int tx = threadIdx.x, ty = threadIdx.y;
    int x = blockIdx.x * 32 + tx, y0 = blockIdx.y * 32;
#pragma unroll
    for (int i = 0; i < 4; i++)
        tile[ty + i * 8][tx] = in[(size_t)(y0 + ty + i * 8) * HIDDEN + x];
    __syncthreads();
    int x2 = blockIdx.y * 32 + tx, y2 = blockIdx.x * 32;
#pragma unroll
    for (int i = 0; i < 4; i++)
        out[(size_t)(y2 + ty + i * 8) * HIDDEN + x2] = f2bf(tile[tx][ty + i * 8]);
}

// ---------------- 128x128 bf16 MFMA GEMM: C = A(MxK) * B^T(NxK)^T, z selects B/C
template <int OUTB>
__global__ __launch_bounds__(256) void k_gemm128(
    const unsigned short* __restrict__ A,
    const unsigned short* __restrict__ B0, const unsigned short* __restrict__ B1,
    const unsigned short* __restrict__ B2,
    void* __restrict__ C0, void* __restrict__ C1, void* __restrict__ C2,
    int M, int N, int K)
{
    __shared__ __align__(16) unsigned short As[128 * 72];
    __shared__ __align__(16) unsigned short Bs[128 * 72];
    const int z = blockIdx.z;
    const unsigned short* Bm = (z == 0) ? B0 : (z == 1 ? B1 : B2);
    void* Cv = (z == 0) ? C0 : (z == 1 ? C1 : C2);
    const int tid = threadIdx.x, l = tid & 63, w = tid >> 6;
    const int wm = w >> 1, wn = w & 1;
    const int m0 = blockIdx.y * 128, n0 = blockIdx.x * 128;
    const int lr = l & 15, lg = l >> 4;
    f32x4 acc[4][4] = {};
    for (int k0 = 0; k0 < K; k0 += 64) {
        __syncthreads();
#pragma unroll
        for (int c = 0; c < 4; c++) {
            int cc = tid + c * 256;                // 1024 chunks: full 128x64 tile
            int row = cc >> 3, ch = cc & 7;
            *(i32x4*)&As[row * 72 + ch * 8] =
                *(const i32x4*)&A[(size_t)(m0 + row) * K + k0 + ch * 8];
            *(i32x4*)&Bs[row * 72 + ch * 8] =
                *(const i32x4*)&Bm[(size_t)(n0 + row) * K + k0 + ch * 8];
        }
        __syncthreads();
#pragma unroll
        for (int kk = 0; kk < 2; kk++) {
            i32x4 af[4], bfr[4];
#pragma unroll
            for (int i = 0; i < 4; i++)
                af[i] = *(const i32x4*)&As[(wm * 64 + i * 16 + lr) * 72 + kk * 32 + lg * 8];
#pragma unroll
            for (int j = 0; j < 4; j++)
                bfr[j] = *(const i32x4*)&Bs[(wn * 64 + j * 16 + lr) * 72 + kk * 32 + lg * 8];
#pragma unroll
            for (int i = 0; i < 4; i++)
#pragma unroll
                for (int j = 0; j < 4; j++)
                    acc[i][j] = __builtin_amdgcn_mfma_f32_16x16x32_bf16(
                        __builtin_bit_cast(bf16x8, af[i]),
                        __builtin_bit_cast(bf16x8, bfr[j]), acc[i][j], 0, 0, 0);
        }
    }
#pragma unroll
    for (int i = 0; i < 4; i++)
#pragma unroll
        for (int j = 0; j < 4; j++)
#pragma unroll
            for (int r = 0; r < 4; r++) {
                int m = m0 + wm * 64 + i * 16 + lg * 4 + r;
                int n = n0 + wn * 64 + j * 16 + lr;
                float v = acc[i][j][r];
                if (OUTB) ((unsigned short*)Cv)[(size_t)m * N + n] = f2bf(v);
                else      ((float*)Cv)[(size_t)m * N + n] = v;
            }
}

// ---------------- RoPE in-place on Q,K: out[d] = x[d]*cos + x[(d-1)%128]*sin
__global__ void k_rope(unsigned short* __restrict__ Q, unsigned short* __restrict__ Kb,
                       const float* __restrict__ ctab, const float* __restrict__ stab)
{
    const int tid = threadIdx.x, l = tid & 63, w = tid >> 6;
    int hr = blockIdx.x * 4 + w;                 // head-row id, one wave each
    unsigned short* X = blockIdx.y ? Kb : Q;
    int bt = hr >> 4, h = hr & 15, t = bt & (SEQ - 1);
    size_t base = (size_t)bt * HIDDEN + h * HDIM;
    int d0 = l * 2;
    ushort2 xv = *(const ushort2*)&X[base + d0];
    float x0 = bf2f(xv.x), x1 = bf2f(xv.y);
    float prev = __shfl(x1, (l + 63) & 63);      // x[d0-1], lane0 wraps to x[127]
    int i0 = d0 & 63, i1 = (d0 + 1) & 63;
    float c0 = ctab[t * 64 + i0], s0 = stab[t * 64 + i0];
    float c1 = ctab[t * 64 + i1], s1 = stab[t * 64 + i1];
    ushort2 ov;
    ov.x = f2bf(x0 * c0 + prev * s0);
    ov.y = f2bf(x1 * c1 + x0 * s1);
    *(ushort2*)&X[base + d0] = ov;
}

// ---------------- V[bt][h*128+d] -> Vt[bh][d][t]  (per-(b,h) transpose)
__global__ void k_vtrans(const unsigned short* __restrict__ V, unsigned short* __restrict__ Vt)
{
    __shared__ unsigned short tile[32][33];
    int z = blockIdx.z;                     // bh
    int b = z >> 4, h = z & 15;
    int tx = threadIdx.x, ty = threadIdx.y;
    int d0 = blockIdx.x * 32, t0 = blockIdx.y * 32;
    const size_t ibase = (size_t)b * SEQ * HIDDEN + h * HDIM;
#pragma unroll
    for (int i = 0; i < 4; i++)
        tile[ty + i * 8][tx] = V[ibase + (size_t)(t0 + ty + i * 8) * HIDDEN + d0 + tx];
    __syncthreads();
    const size_t obase = (size_t)z * HDIM * SEQ;
#pragma unroll
    for (int i = 0; i < 4; i++)
        Vt[obase + (size_t)(d0 + ty + i * 8) * SEQ + t0 + tx] = tile[tx][ty + i * 8];
}

// ---------------- flash attention: QBLK=64 (4 waves x 16 rows), KV tile 32
__global__ __launch_bounds__(256) void k_attn(
    const unsigned short* __restrict__ Q, const unsigned short* __restrict__ K,
    const unsigned short* __restrict__ Vt, unsigned short* __restrict__ ctx)
{
    __shared__ __align__(16) unsigned short Klds[32 * 136];
    __shared__ __align__(16) unsigned short Vlds[128 * 40];
    __shared__ __align__(16) unsigned short Plds[4][16 * 40];
    const int tid = threadIdx.x, l = tid & 63, w = tid >> 6;
    const int lr = l & 15, lg = l >> 4;
    const int q0 = blockIdx.x * 64;
    const int bh = blockIdx.y, b = bh >> 4, h = bh & 15;

    const int qrow = q0 + w * 16 + lr;
    const unsigned short* qbase = Q + (size_t)(b * SEQ + qrow) * HIDDEN + h * HDIM + lg * 8;
    i32x4 qf[4];
#pragma unroll
    for (int c = 0; c < 4; c++) qf[c] = *(const i32x4*)(qbase + c * 32);

    f32x4 acc[8] = {};
    float mrow[4] = {-1e30f, -1e30f, -1e30f, -1e30f};
    float lrow[4] = {0.f, 0.f, 0.f, 0.f};
    const float scale = 0.08838834764831845f;   // 1/sqrt(128)

    for (int t0 = 0; t0 < SEQ; t0 += 32) {
        __syncthreads();
#pragma unroll
        for (int c = 0; c < 2; c++) {
            int cc = tid + c * 256;
            {   int r = cc >> 4, ch = cc & 15;
                *(i32x4*)&Klds[r * 136 + ch * 8] =
                    *(const i32x4*)&K[(size_t)(b * SEQ + t0 + r) * HIDDEN + h * HDIM + ch * 8]; }
            {   int d = cc >> 2, ch = cc & 3;
                *(i32x4*)&Vlds[d * 40 + ch * 8] =
                    *(const i32x4*)&Vt[(size_t)(bh * HDIM + d) * SEQ + t0 + ch * 8]; }
        }
        __syncthreads();

        f32x4 s[2] = {};
#pragma unroll
        for (int ks = 0; ks < 2; ks++)
#pragma unroll
            for (int c = 0; c < 4; c++) {
                i32x4 kf = *(const i32x4*)&Klds[(ks * 16 + lr) * 136 + c * 32 + lg * 8];
                s[ks] = __builtin_amdgcn_mfma_f32_16x16x32_bf16(
                    __builtin_bit_cast(bf16x8, qf[c]), __builtin_bit_cast(bf16x8, kf),
                    s[ks], 0, 0, 0);
            }

        unsigned short* pw = &Plds[w][0];
#pragma unroll
        for (int r = 0; r < 4; r++) {
            float a0 = s[0][r] * scale, a1 = s[1][r] * scale;
            float v = fmaxf(a0, a1);
            v = fmaxf(v, __shfl_xor(v, 1));
            v = fmaxf(v, __shfl_xor(v, 2));
            v = fmaxf(v, __shfl_xor(v, 4));
            v = fmaxf(v, __shfl_xor(v, 8));
            float mn = fmaxf(mrow[r], v);
            float p0 = __expf(a0 - mn), p1 = __expf(a1 - mn);
            float sm = p0 + p1;
            sm += __shfl_xor(sm, 1);
            sm += __shfl_xor(sm, 2);
            sm += __shfl_xor(sm, 4);
            sm += __shfl_xor(sm, 8);
            float fac = __expf(mrow[r] - mn);
            mrow[r] = mn;
            lrow[r] = lrow[r] * fac + sm;
            pw[(lg * 4 + r) * 40 + lr]      = f2bf(p0);
            pw[(lg * 4 + r) * 40 + 16 + lr] = f2bf(p1);
#pragma unroll
            for (int db = 0; db < 8; db++) acc[db][r] *= fac;
        }

        i32x4 pf = *(const i32x4*)&Plds[w][lr * 40 + lg * 8];
#pragma unroll
        for (int db = 0; db < 8; db++) {
            i32x4 vf = *(const i32x4*)&Vlds[(db * 16 + lr) * 40 + lg * 8];
            acc[db] = __builtin_amdgcn_mfma_f32_16x16x32_bf16(
                __builtin_bit_cast(bf16x8, pf), __builtin_bit_cast(bf16x8, vf),
                acc[db], 0, 0, 0);
        }
    }

    float inv[4];
#pragma unroll
    for (int r = 0; r < 4; r++) inv[r] = 1.0f / lrow[r];
#pragma unroll
    for (int db = 0; db < 8; db++)
#pragma unroll
        for (int r = 0; r < 4; r++) {
            int trow = q0 + w * 16 + lg * 4 + r;
            ctx[(size_t)(b * SEQ + trow) * HIDDEN + h * HDIM + db * 16 + lr] =
                f2bf(acc[db][r] * inv[r]);
        }
}

extern "C" void kernel_launch(void* const* d_in, const int* in_sizes, int n_in,
                              void* d_out, int out_size, void* d_ws, size_t ws_size,
                              hipStream_t stream)
{
    (void)in_sizes; (void)n_in; (void)out_size; (void)ws_size;
    const float* X  = (const float*)d_in[0];
    const float* Wq = (const float*)d_in[1];
    const float* Wk = (const float*)d_in[2];
    const float* Wv = (const float*)d_in[3];
    const float* Wo = (const float*)d_in[4];
    float* out = (float*)d_out;
    char* ws = (char*)d_ws;

    unsigned short* Xb  = (unsigned short*)(ws);                 // 16 MB  (4096x2048 bf16)
    unsigned short* WqT = (unsigned short*)(ws + 16777216);      // 8 MB each, N x K bf16
    unsigned short* WkT = (unsigned short*)(ws + 25165824);
    unsigned short* WvT = (unsigned short*)(ws + 33554432);
    unsigned short* WoT = (unsigned short*)(ws + 41943040);
    unsigned short* Qb  = (unsigned short*)(ws + 50331648);      // 16 MB each
    unsigned short* Kb  = (unsigned short*)(ws + 67108864);
    unsigned short* Vb  = (unsigned short*)(ws + 83886080);
    unsigned short* Vt  = (unsigned short*)(ws + 100663296);
    unsigned short* Cx  = (unsigned short*)(ws + 117440512);
    float* ctab = (float*)(ws + 134217728);                      // 0.5 MB each
    float* stab = (float*)(ws + 134742016);

    k_rope_tables<<<512, 256, 0, stream>>>(ctab, stab);
    k_cvt_bf16<<<8192, 256, 0, stream>>>(X, Xb, 2097152);
    k_transcvt<<<dim3(64, 64), dim3(32, 8), 0, stream>>>(Wq, WqT);
    k_transcvt<<<dim3(64, 64), dim3(32, 8), 0, stream>>>(Wk, WkT);
    k_transcvt<<<dim3(64, 64), dim3(32, 8), 0, stream>>>(Wv, WvT);
    k_transcvt<<<dim3(64, 64), dim3(32, 8), 0, stream>>>(Wo, WoT);
    k_gemm128<1><<<dim3(16, 32, 3), 256, 0, stream>>>(Xb, WqT, WkT, WvT,
                                                      Qb, Kb, Vb, 4096, 2048, 2048);
    k_rope<<<dim3(16384, 2), 256, 0, stream>>>(Qb, Kb, ctab, stab);
    k_vtrans<<<dim3(4, 64, 32), dim3(32, 8), 0, stream>>>(Vb, Vt);
    k_attn<<<dim3(32, 32), 256, 0, stream>>>(Qb, Kb, Vt, Cx);
    k_gemm128<0><<<dim3(16, 32, 1), 256, 0, stream>>>(Cx, WoT, WoT, WoT,
                                                      out, out, out, 4096, 2048, 2048);
}

// Round 3
// 415.418 us; speedup vs baseline: 1.1900x; 1.1900x over previous
//
#include <hip/hip_runtime.h>

#define HIDDEN 2048
#define SEQ    2048
#define BATCH  2
#define NHEAD  16
#define HDIM   128

typedef __attribute__((ext_vector_type(4))) int    i32x4;
typedef __attribute__((ext_vector_type(4))) float  f32x4;
typedef __attribute__((ext_vector_type(8))) __bf16 bf16x8;

__device__ __forceinline__ unsigned short f2bf(float f) {
    unsigned u = __builtin_bit_cast(unsigned, f);
    u += 0x7FFFu + ((u >> 16) & 1u);   // RNE (no NaN inputs in this pipeline)
    return (unsigned short)(u >> 16);
}
__device__ __forceinline__ float bf2f(unsigned short h) {
    unsigned u = ((unsigned)h) << 16;
    return __builtin_bit_cast(float, u);
}
// async global->LDS, 16B per lane; dest must be wave-uniform base + lane*16
__device__ __forceinline__ void gl_lds16(const unsigned short* g, unsigned short* l) {
    __builtin_amdgcn_global_load_lds(
        (const __attribute__((address_space(1))) unsigned int*)g,
        (__attribute__((address_space(3))) unsigned int*)l, 16, 0, 0);
}

// ---------------- RoPE tables: ctab/stab[t*64 + i] = cos/sin(t * 10000^(-i/64))
__global__ void k_rope_tables(float* __restrict__ ctab, float* __restrict__ stab) {
    int idx = blockIdx.x * 256 + threadIdx.x;      // exactly SEQ*64 threads
    int t = idx >> 6, i = idx & 63;
    float inv = expf(-(float)i * 0.14391156831212793f);  // ln(10000)/64
    float ang = (float)t * inv;
    ctab[idx] = cosf(ang);
    stab[idx] = sinf(ang);
}

// ---------------- fp32 -> bf16 convert (4 elems/thread)
__global__ void k_cvt_bf16(const float* __restrict__ in, unsigned short* __restrict__ out, int n4) {
    int idx = blockIdx.x * blockDim.x + threadIdx.x;
    if (idx < n4) {
        float4 v = ((const float4*)in)[idx];
        ushort4 o;
        o.x = f2bf(v.x); o.y = f2bf(v.y); o.z = f2bf(v.z); o.w = f2bf(v.w);
        ((ushort4*)out)[idx] = o;
    }
}

// ---------------- W (K x N fp32) -> W^T (N x K bf16), 32x32 LDS tiles
__global__ void k_transcvt(const float* __restrict__ in, unsigned short* __restrict__ out) {
    __shared__ float tile[32][33];
    int tx = threadIdx.x, ty = threadIdx.y;
    int x = blockIdx.x * 32 + tx, y0 = blockIdx.y * 32;
#pragma unroll
    for (int i = 0; i < 4; i++)
        tile[ty + i * 8][tx] = in[(size_t)(y0 + ty + i * 8) * HIDDEN + x];
    __syncthreads();
    int x2 = blockIdx.y * 32 + tx, y2 = blockIdx.x * 32;
#pragma unroll
    for (int i = 0; i < 4; i++)
        out[(size_t)(y2 + ty + i * 8) * HIDDEN + x2] = f2bf(tile[tx][ty + i * 8]);
}

// ---------------- 128x128 bf16 MFMA GEMM (m97 structure: global_load_lds, linear LDS)
template <int OUTB>
__global__ __launch_bounds__(256) void k_gemm128(
    const unsigned short* __restrict__ A,
    const unsigned short* __restrict__ B0, const unsigned short* __restrict__ B1,
    const unsigned short* __restrict__ B2,
    void* __restrict__ C0, void* __restrict__ C1, void* __restrict__ C2,
    int M, int N, int K)
{
    __shared__ __align__(16) unsigned short As[128 * 64];
    __shared__ __align__(16) unsigned short Bs[128 * 64];
    const int z = blockIdx.z;
    const unsigned short* Bm = (z == 0) ? B0 : (z == 1 ? B1 : B2);
    void* Cv = (z == 0) ? C0 : (z == 1 ? C1 : C2);
    const int tid = threadIdx.x, l = tid & 63, w = tid >> 6;
    const int wm = w >> 1, wn = w & 1;
    const int m0 = blockIdx.y * 128, n0 = blockIdx.x * 128;
    const int lr = l & 15, lg = l >> 4;

    const unsigned short* ag[4];
    const unsigned short* bg[4];
    int ld[4];
#pragma unroll
    for (int c = 0; c < 4; c++) {
        int cc = tid + c * 256;                // 1024 chunks: full 128x64 tile
        int row = cc >> 3, ch = cc & 7;
        ag[c] = A  + (size_t)(m0 + row) * K + ch * 8;
        bg[c] = Bm + (size_t)(n0 + row) * K + ch * 8;
        ld[c] = cc * 8;
    }

    f32x4 acc[4][4] = {};
    for (int k0 = 0; k0 < K; k0 += 64) {
        __syncthreads();
#pragma unroll
        for (int c = 0; c < 4; c++) {
            gl_lds16(ag[c] + k0, &As[ld[c]]);
            gl_lds16(bg[c] + k0, &Bs[ld[c]]);
        }
        __syncthreads();
#pragma unroll
        for (int kk = 0; kk < 2; kk++) {
            i32x4 af[4], bfr[4];
#pragma unroll
            for (int i = 0; i < 4; i++)
                af[i] = *(const i32x4*)&As[(wm * 64 + i * 16 + lr) * 64 + kk * 32 + lg * 8];
#pragma unroll
            for (int j = 0; j < 4; j++)
                bfr[j] = *(const i32x4*)&Bs[(wn * 64 + j * 16 + lr) * 64 + kk * 32 + lg * 8];
#pragma unroll
            for (int i = 0; i < 4; i++)
#pragma unroll
                for (int j = 0; j < 4; j++)
                    acc[i][j] = __builtin_amdgcn_mfma_f32_16x16x32_bf16(
                        __builtin_bit_cast(bf16x8, af[i]),
                        __builtin_bit_cast(bf16x8, bfr[j]), acc[i][j], 0, 0, 0);
        }
    }
#pragma unroll
    for (int i = 0; i < 4; i++)
#pragma unroll
        for (int j = 0; j < 4; j++)
#pragma unroll
            for (int r = 0; r < 4; r++) {
                int m = m0 + wm * 64 + i * 16 + lg * 4 + r;
                int n = n0 + wn * 64 + j * 16 + lr;
                float v = acc[i][j][r];
                if (OUTB) ((unsigned short*)Cv)[(size_t)m * N + n] = f2bf(v);
                else      ((float*)Cv)[(size_t)m * N + n] = v;
            }
}

// ---------------- RoPE in-place on Q,K; Q additionally scaled by 1/sqrt(D)
__global__ void k_rope(unsigned short* __restrict__ Q, unsigned short* __restrict__ Kb,
                       const float* __restrict__ ctab, const float* __restrict__ stab)
{
    const int tid = threadIdx.x, l = tid & 63, w = tid >> 6;
    int hr = blockIdx.x * 4 + w;                 // head-row id, one wave each
    unsigned short* X = blockIdx.y ? Kb : Q;
    float sc = blockIdx.y ? 1.0f : 0.08838834764831845f;   // 1/sqrt(128) folded into Q
    int bt = hr >> 4, h = hr & 15, t = bt & (SEQ - 1);
    size_t base = (size_t)bt * HIDDEN + h * HDIM;
    int d0 = l * 2;
    ushort2 xv = *(const ushort2*)&X[base + d0];
    float x0 = bf2f(xv.x), x1 = bf2f(xv.y);
    float prev = __shfl(x1, (l + 63) & 63);      // x[d0-1], lane0 wraps to x[127]
    int i0 = d0 & 63, i1 = (d0 + 1) & 63;
    float c0 = ctab[t * 64 + i0], s0 = stab[t * 64 + i0];
    float c1 = ctab[t * 64 + i1], s1 = stab[t * 64 + i1];
    ushort2 ov;
    ov.x = f2bf((x0 * c0 + prev * s0) * sc);
    ov.y = f2bf((x1 * c1 + x0 * s1) * sc);
    *(ushort2*)&X[base + d0] = ov;
}

// ---------------- V[bt][h*128+d] -> Vt[bh][d][t]  (per-(b,h) transpose)
__global__ void k_vtrans(const unsigned short* __restrict__ V, unsigned short* __restrict__ Vt)
{
    __shared__ unsigned short tile[32][33];
    int z = blockIdx.z;                     // bh
    int b = z >> 4, h = z & 15;
    int tx = threadIdx.x, ty = threadIdx.y;
    int d0 = blockIdx.x * 32, t0 = blockIdx.y * 32;
    const size_t ibase = (size_t)b * SEQ * HIDDEN + h * HDIM;
#pragma unroll
    for (int i = 0; i < 4; i++)
        tile[ty + i * 8][tx] = V[ibase + (size_t)(t0 + ty + i * 8) * HIDDEN + d0 + tx];
    __syncthreads();
    const size_t obase = (size_t)z * HDIM * SEQ;
#pragma unroll
    for (int i = 0; i < 4; i++)
        Vt[obase + (size_t)(d0 + ty + i * 8) * SEQ + t0 + tx] = tile[tx][ty + i * 8];
}

// ---------------- flash attention: QBLK=64 (4 waves x 16 rows), KV tile 64
// K/V staged via global_load_lds with pre-swizzled source (involution ch^=(row&7)),
// swizzle re-applied on ds_read -> conflict-free. Defer-rescale (T13, THR=8).
__global__ __launch_bounds__(256) void k_attn(
    const unsigned short* __restrict__ Q, const unsigned short* __restrict__ K,
    const unsigned short* __restrict__ Vt, unsigned short* __restrict__ ctx)
{
    __shared__ __align__(16) unsigned short Klds[64 * 128];
    __shared__ __align__(16) unsigned short Vlds[128 * 64];
    __shared__ __align__(16) unsigned short Plds[4][16 * 72];
    const int tid = threadIdx.x, l = tid & 63, w = tid >> 6;
    const int lr = l & 15, lg = l >> 4;
    const int q0 = blockIdx.x * 64;
    const int bh = blockIdx.y, b = bh >> 4, h = bh & 15;

    const int qrow = q0 + w * 16 + lr;
    const unsigned short* qbase = Q + (size_t)(b * SEQ + qrow) * HIDDEN + h * HDIM + lg * 8;
    i32x4 qf[4];
#pragma unroll
    for (int c = 0; c < 4; c++) qf[c] = *(const i32x4*)(qbase + c * 32);

    // staging pointers: 4 K-chunks + 4 V-chunks per thread, source pre-swizzled
    const unsigned short* kg[4];
    const unsigned short* vg[4];
    int kl[4], vl[4];
#pragma unroll
    for (int c = 0; c < 4; c++) {
        int cc = tid + c * 256;
        {   int row = cc >> 4, ch = cc & 15, sch = ch ^ (row & 7);
            kg[c] = K + (size_t)(b * SEQ + row) * HIDDEN + h * HDIM + sch * 8;
            kl[c] = cc * 8; }
        {   int row = cc >> 3, ch = cc & 7, sch = ch ^ (row & 7);
            vg[c] = Vt + (size_t)(bh * HDIM + row) * SEQ + sch * 8;
            vl[c] = cc * 8; }
    }

    f32x4 acc[8] = {};
    float mrow[4] = {-1e30f, -1e30f, -1e30f, -1e30f};
    float lrow[4] = {0.f, 0.f, 0.f, 0.f};

    for (int t0 = 0; t0 < SEQ; t0 += 64) {
        __syncthreads();
#pragma unroll
        for (int c = 0; c < 4; c++) {
            gl_lds16(kg[c], &Klds[kl[c]]);  kg[c] += 64 * HIDDEN;
            gl_lds16(vg[c], &Vlds[vl[c]]);  vg[c] += 64;
        }
        __syncthreads();

        // QK^T: S[16 q-rows][64 k-cols] per wave (Q pre-scaled by 1/sqrt(D))
        f32x4 s[4];
#pragma unroll
        for (int ks = 0; ks < 4; ks++) {
            s[ks] = f32x4{0.f, 0.f, 0.f, 0.f};
#pragma unroll
            for (int c = 0; c < 4; c++) {
                i32x4 kf = *(const i32x4*)&Klds[(ks * 16 + lr) * 128 + ((c * 4 + lg) ^ (lr & 7)) * 8];
                s[ks] = __builtin_amdgcn_mfma_f32_16x16x32_bf16(
                    __builtin_bit_cast(bf16x8, qf[c]), __builtin_bit_cast(bf16x8, kf),
                    s[ks], 0, 0, 0);
            }
        }

        unsigned short* pw = &Plds[w][0];
        float fac[4];
        bool anyneed = false;
#pragma unroll
        for (int r = 0; r < 4; r++) {
            float a0 = s[0][r], a1 = s[1][r], a2 = s[2][r], a3 = s[3][r];
            float v = fmaxf(fmaxf(a0, a1), fmaxf(a2, a3));
            v = fmaxf(v, __shfl_xor(v, 1));
            v = fmaxf(v, __shfl_xor(v, 2));
            v = fmaxf(v, __shfl_xor(v, 4));
            v = fmaxf(v, __shfl_xor(v, 8));
            bool need = v > mrow[r] + 8.0f;          // defer-rescale: P bounded by e^8
            float mn = need ? v : mrow[r];
            fac[r] = need ? __expf(mrow[r] - v) : 1.0f;
            mrow[r] = mn;
            float p0 = __expf(a0 - mn), p1 = __expf(a1 - mn);
            float p2 = __expf(a2 - mn), p3 = __expf(a3 - mn);
            float sm = p0 + p1 + p2 + p3;
            sm += __shfl_xor(sm, 1);
            sm += __shfl_xor(sm, 2);
            sm += __shfl_xor(sm, 4);
            sm += __shfl_xor(sm, 8);
            lrow[r] = lrow[r] * fac[r] + sm;
            int prow = (lg * 4 + r) * 72;
            pw[prow + lr]      = f2bf(p0);
            pw[prow + 16 + lr] = f2bf(p1);
            pw[prow + 32 + lr] = f2bf(p2);
            pw[prow + 48 + lr] = f2bf(p3);
            anyneed |= need;
        }
        if (__any(anyneed)) {
#pragma unroll
            for (int db = 0; db < 8; db++)
#pragma unroll
                for (int r = 0; r < 4; r++) acc[db][r] *= fac[r];
        }

#pragma unroll
        for (int kk = 0; kk < 2; kk++) {
            i32x4 pf = *(const i32x4*)&Plds[w][lr * 72 + kk * 32 + lg * 8];
#pragma unroll
            for (int db = 0; db < 8; db++) {
                i32x4 vf = *(const i32x4*)&Vlds[(db * 16 + lr) * 64 + ((kk * 4 + lg) ^ (lr & 7)) * 8];
                acc[db] = __builtin_amdgcn_mfma_f32_16x16x32_bf16(
                    __builtin_bit_cast(bf16x8, pf), __builtin_bit_cast(bf16x8, vf),
                    acc[db], 0, 0, 0);
            }
        }
    }

    float inv[4];
#pragma unroll
    for (int r = 0; r < 4; r++) inv[r] = 1.0f / lrow[r];
#pragma unroll
    for (int db = 0; db < 8; db++)
#pragma unroll
        for (int r = 0; r < 4; r++) {
            int trow = q0 + w * 16 + lg * 4 + r;
            ctx[(size_t)(b * SEQ + trow) * HIDDEN + h * HDIM + db * 16 + lr] =
                f2bf(acc[db][r] * inv[r]);
        }
}

extern "C" void kernel_launch(void* const* d_in, const int* in_sizes, int n_in,
                              void* d_out, int out_size, void* d_ws, size_t ws_size,
                              hipStream_t stream)
{
    (void)in_sizes; (void)n_in; (void)out_size; (void)ws_size;
    const float* X  = (const float*)d_in[0];
    const float* Wq = (const float*)d_in[1];
    const float* Wk = (const float*)d_in[2];
    const float* Wv = (const float*)d_in[3];
    const float* Wo = (const float*)d_in[4];
    float* out = (float*)d_out;
    char* ws = (char*)d_ws;

    unsigned short* Xb  = (unsigned short*)(ws);                 // 16 MB  (4096x2048 bf16)
    unsigned short* WqT = (unsigned short*)(ws + 16777216);      // 8 MB each, N x K bf16
    unsigned short* WkT = (unsigned short*)(ws + 25165824);
    unsigned short* WvT = (unsigned short*)(ws + 33554432);
    unsigned short* WoT = (unsigned short*)(ws + 41943040);
    unsigned short* Qb  = (unsigned short*)(ws + 50331648);      // 16 MB each
    unsigned short* Kb  = (unsigned short*)(ws + 67108864);
    unsigned short* Vb  = (unsigned short*)(ws + 83886080);
    unsigned short* Vt  = (unsigned short*)(ws + 100663296);
    unsigned short* Cx  = (unsigned short*)(ws + 117440512);
    float* ctab = (float*)(ws + 134217728);                      // 0.5 MB each
    float* stab = (float*)(ws + 134742016);

    k_rope_tables<<<512, 256, 0, stream>>>(ctab, stab);
    k_cvt_bf16<<<8192, 256, 0, stream>>>(X, Xb, 2097152);
    k_transcvt<<<dim3(64, 64), dim3(32, 8), 0, stream>>>(Wq, WqT);
    k_transcvt<<<dim3(64, 64), dim3(32, 8), 0, stream>>>(Wk, WkT);
    k_transcvt<<<dim3(64, 64), dim3(32, 8), 0, stream>>>(Wv, WvT);
    k_transcvt<<<dim3(64, 64), dim3(32, 8), 0, stream>>>(Wo, WoT);
    k_gemm128<1><<<dim3(16, 32, 3), 256, 0, stream>>>(Xb, WqT, WkT, WvT,
                                                      Qb, Kb, Vb, 4096, 2048, 2048);
    k_rope<<<dim3(16384, 2), 256, 0, stream>>>(Qb, Kb, ctab, stab);
    k_vtrans<<<dim3(4, 64, 32), dim3(32, 8), 0, stream>>>(Vb, Vt);
    k_attn<<<dim3(32, 32), 256, 0, stream>>>(Qb, Kb, Vt, Cx);
    k_gemm128<0><<<dim3(16, 32, 1), 256, 0, stream>>>(Cx, WoT, WoT, WoT,
                                                      out, out, out, 4096, 2048, 2048);
}

// Round 4
// 389.962 us; speedup vs baseline: 1.2676x; 1.0653x over previous
//
#include <hip/hip_runtime.h>

#define HIDDEN 2048
#define SEQ    2048
#define BATCH  2
#define NHEAD  16
#define HDIM   128

typedef __attribute__((ext_vector_type(4))) int    i32x4;
typedef __attribute__((ext_vector_type(4))) float  f32x4;
typedef __attribute__((ext_vector_type(8))) __bf16 bf16x8;

__device__ __forceinline__ unsigned short f2bf(float f) {
    unsigned u = __builtin_bit_cast(unsigned, f);
    u += 0x7FFFu + ((u >> 16) & 1u);   // RNE (no NaN inputs in this pipeline)
    return (unsigned short)(u >> 16);
}
__device__ __forceinline__ float bf2f(unsigned short h) {
    unsigned u = ((unsigned)h) << 16;
    return __builtin_bit_cast(float, u);
}
// async global->LDS, 16B per lane; dest must be wave-uniform base + lane*16
__device__ __forceinline__ void gl_lds16(const unsigned short* g, unsigned short* l) {
    __builtin_amdgcn_global_load_lds(
        (const __attribute__((address_space(1))) unsigned int*)g,
        (__attribute__((address_space(3))) unsigned int*)l, 16, 0, 0);
}

// ---------------- RoPE tables: ctab/stab[t*64 + i] = cos/sin(t * 10000^(-i/64))
__global__ void k_rope_tables(float* __restrict__ ctab, float* __restrict__ stab) {
    int idx = blockIdx.x * 256 + threadIdx.x;      // exactly SEQ*64 threads
    int t = idx >> 6, i = idx & 63;
    float inv = expf(-(float)i * 0.14391156831212793f);  // ln(10000)/64
    float ang = (float)t * inv;
    ctab[idx] = cosf(ang);
    stab[idx] = sinf(ang);
}

// ---------------- fp32 -> bf16 convert (4 elems/thread)
__global__ void k_cvt_bf16(const float* __restrict__ in, unsigned short* __restrict__ out, int n4) {
    int idx = blockIdx.x * blockDim.x + threadIdx.x;
    if (idx < n4) {
        float4 v = ((const float4*)in)[idx];
        ushort4 o;
        o.x = f2bf(v.x); o.y = f2bf(v.y); o.z = f2bf(v.z); o.w = f2bf(v.w);
        ((ushort4*)out)[idx] = o;
    }
}

// ---------------- W (K x N fp32) -> W^T (N x K bf16), 32x32 LDS tiles
__global__ void k_transcvt(const float* __restrict__ in, unsigned short* __restrict__ out) {
    __shared__ float tile[32][33];
    int tx = threadIdx.x, ty = threadIdx.y;
    int x = blockIdx.x * 32 + tx, y0 = blockIdx.y * 32;
#pragma unroll
    for (int i = 0; i < 4; i++)
        tile[ty + i * 8][tx] = in[(size_t)(y0 + ty + i * 8) * HIDDEN + x];
    __syncthreads();
    int x2 = blockIdx.y * 32 + tx, y2 = blockIdx.x * 32;
#pragma unroll
    for (int i = 0; i < 4; i++)
        out[(size_t)(y2 + ty + i * 8) * HIDDEN + x2] = f2bf(tile[tx][ty + i * 8]);
}

// ---------------- 128x128 bf16 MFMA GEMM (m97 structure: global_load_lds, linear LDS)
template <int OUTB>
__global__ __launch_bounds__(256) void k_gemm128(
    const unsigned short* __restrict__ A,
    const unsigned short* __restrict__ B0, const unsigned short* __restrict__ B1,
    const unsigned short* __restrict__ B2,
    void* __restrict__ C0, void* __restrict__ C1, void* __restrict__ C2,
    int M, int N, int K)
{
    __shared__ __align__(16) unsigned short As[128 * 64];
    __shared__ __align__(16) unsigned short Bs[128 * 64];
    const int z = blockIdx.z;
    const unsigned short* Bm = (z == 0) ? B0 : (z == 1 ? B1 : B2);
    void* Cv = (z == 0) ? C0 : (z == 1 ? C1 : C2);
    const int tid = threadIdx.x, l = tid & 63, w = tid >> 6;
    const int wm = w >> 1, wn = w & 1;
    const int m0 = blockIdx.y * 128, n0 = blockIdx.x * 128;
    const int lr = l & 15, lg = l >> 4;

    const unsigned short* ag[4];
    const unsigned short* bg[4];
    int ld[4];
#pragma unroll
    for (int c = 0; c < 4; c++) {
        int cc = tid + c * 256;                // 1024 chunks: full 128x64 tile
        int row = cc >> 3, ch = cc & 7;
        ag[c] = A  + (size_t)(m0 + row) * K + ch * 8;
        bg[c] = Bm + (size_t)(n0 + row) * K + ch * 8;
        ld[c] = cc * 8;
    }

    f32x4 acc[4][4] = {};
    for (int k0 = 0; k0 < K; k0 += 64) {
        __syncthreads();
#pragma unroll
        for (int c = 0; c < 4; c++) {
            gl_lds16(ag[c] + k0, &As[ld[c]]);
            gl_lds16(bg[c] + k0, &Bs[ld[c]]);
        }
        __syncthreads();
#pragma unroll
        for (int kk = 0; kk < 2; kk++) {
            i32x4 af[4], bfr[4];
#pragma unroll
            for (int i = 0; i < 4; i++)
                af[i] = *(const i32x4*)&As[(wm * 64 + i * 16 + lr) * 64 + kk * 32 + lg * 8];
#pragma unroll
            for (int j = 0; j < 4; j++)
                bfr[j] = *(const i32x4*)&Bs[(wn * 64 + j * 16 + lr) * 64 + kk * 32 + lg * 8];
#pragma unroll
            for (int i = 0; i < 4; i++)
#pragma unroll
                for (int j = 0; j < 4; j++)
                    acc[i][j] = __builtin_amdgcn_mfma_f32_16x16x32_bf16(
                        __builtin_bit_cast(bf16x8, af[i]),
                        __builtin_bit_cast(bf16x8, bfr[j]), acc[i][j], 0, 0, 0);
        }
    }
#pragma unroll
    for (int i = 0; i < 4; i++)
#pragma unroll
        for (int j = 0; j < 4; j++)
#pragma unroll
            for (int r = 0; r < 4; r++) {
                int m = m0 + wm * 64 + i * 16 + lg * 4 + r;
                int n = n0 + wn * 64 + j * 16 + lr;
                float v = acc[i][j][r];
                if (OUTB) ((unsigned short*)Cv)[(size_t)m * N + n] = f2bf(v);
                else      ((float*)Cv)[(size_t)m * N + n] = v;
            }
}

// ---------------- RoPE in-place on Q,K; Q additionally scaled by 1/sqrt(D)
__global__ void k_rope(unsigned short* __restrict__ Q, unsigned short* __restrict__ Kb,
                       const float* __restrict__ ctab, const float* __restrict__ stab)
{
    const int tid = threadIdx.x, l = tid & 63, w = tid >> 6;
    int hr = blockIdx.x * 4 + w;                 // head-row id, one wave each
    unsigned short* X = blockIdx.y ? Kb : Q;
    float sc = blockIdx.y ? 1.0f : 0.08838834764831845f;   // 1/sqrt(128) folded into Q
    int bt = hr >> 4, h = hr & 15, t = bt & (SEQ - 1);
    size_t base = (size_t)bt * HIDDEN + h * HDIM;
    int d0 = l * 2;
    ushort2 xv = *(const ushort2*)&X[base + d0];
    float x0 = bf2f(xv.x), x1 = bf2f(xv.y);
    float prev = __shfl(x1, (l + 63) & 63);      // x[d0-1], lane0 wraps to x[127]
    int i0 = d0 & 63, i1 = (d0 + 1) & 63;
    float c0 = ctab[t * 64 + i0], s0 = stab[t * 64 + i0];
    float c1 = ctab[t * 64 + i1], s1 = stab[t * 64 + i1];
    ushort2 ov;
    ov.x = f2bf((x0 * c0 + prev * s0) * sc);
    ov.y = f2bf((x1 * c1 + x0 * s1) * sc);
    *(ushort2*)&X[base + d0] = ov;
}

// ---------------- V[bt][h*128+d] -> Vt[bh][d][t]  (per-(b,h) transpose)
__global__ void k_vtrans(const unsigned short* __restrict__ V, unsigned short* __restrict__ Vt)
{
    __shared__ unsigned short tile[32][33];
    int z = blockIdx.z;                     // bh
    int b = z >> 4, h = z & 15;
    int tx = threadIdx.x, ty = threadIdx.y;
    int d0 = blockIdx.x * 32, t0 = blockIdx.y * 32;
    const size_t ibase = (size_t)b * SEQ * HIDDEN + h * HDIM;
#pragma unroll
    for (int i = 0; i < 4; i++)
        tile[ty + i * 8][tx] = V[ibase + (size_t)(t0 + ty + i * 8) * HIDDEN + d0 + tx];
    __syncthreads();
    const size_t obase = (size_t)z * HDIM * SEQ;
#pragma unroll
    for (int i = 0; i < 4; i++)
        Vt[obase + (size_t)(d0 + ty + i * 8) * SEQ + t0 + tx] = tile[tx][ty + i * 8];
}

// ---------------- flash attention, swapped-QK^T (T12 structure adaptation)
// mfma(K,Q) puts S[q=lr][kv=slice*16+lg*4+r] lane-local per q-row:
// row softmax = in-register tree + 2 shfl_xor. P via swizzled LDS (4 b64 stores).
__global__ __launch_bounds__(256) void k_attn(
    const unsigned short* __restrict__ Q, const unsigned short* __restrict__ K,
    const unsigned short* __restrict__ Vt, unsigned short* __restrict__ ctx)
{
    __shared__ __align__(16) unsigned short Klds[64 * 128];
    __shared__ __align__(16) unsigned short Vlds[128 * 64];
    __shared__ __align__(16) unsigned short Plds[4][16 * 64];
    const int tid = threadIdx.x, l = tid & 63, w = tid >> 6;
    const int lr = l & 15, lg = l >> 4;
    const int q0 = blockIdx.x * 64;
    const int bh = blockIdx.y, b = bh >> 4, h = bh & 15;

    const int qrow = q0 + w * 16 + lr;
    const unsigned short* qbase = Q + (size_t)(b * SEQ + qrow) * HIDDEN + h * HDIM + lg * 8;
    i32x4 qf[4];
#pragma unroll
    for (int c = 0; c < 4; c++) qf[c] = *(const i32x4*)(qbase + c * 32);

    // staging pointers: 4 K-chunks + 4 V-chunks per thread, source pre-swizzled
    const unsigned short* kg[4];
    const unsigned short* vg[4];
    int kl[4], vl[4];
#pragma unroll
    for (int c = 0; c < 4; c++) {
        int cc = tid + c * 256;
        {   int row = cc >> 4, ch = cc & 15, sch = ch ^ (row & 7);
            kg[c] = K + (size_t)(b * SEQ + row) * HIDDEN + h * HDIM + sch * 8;
            kl[c] = cc * 8; }
        {   int row = cc >> 3, ch = cc & 7, sch = ch ^ (row & 7);
            vg[c] = Vt + (size_t)(bh * HDIM + row) * SEQ + sch * 8;
            vl[c] = cc * 8; }
    }

    f32x4 acc[8] = {};
    float m_run = -1e30f, l_run = 0.f;      // per-lane stats for q-row q0+w*16+lr

    for (int t0 = 0; t0 < SEQ; t0 += 64) {
        __syncthreads();
#pragma unroll
        for (int c = 0; c < 4; c++) {
            gl_lds16(kg[c], &Klds[kl[c]]);  kg[c] += 64 * HIDDEN;
            gl_lds16(vg[c], &Vlds[vl[c]]);  vg[c] += 64;
        }
        __syncthreads();

        // swapped QK^T: mfma(K,Q) -> lane(lr,lg) reg r = S[q=lr][kv=slice*16+lg*4+r]
        f32x4 s[4];
        __builtin_amdgcn_s_setprio(1);
#pragma unroll
        for (int ks = 0; ks < 4; ks++) {
            s[ks] = f32x4{0.f, 0.f, 0.f, 0.f};
#pragma unroll
            for (int c = 0; c < 4; c++) {
                i32x4 kf = *(const i32x4*)&Klds[(ks * 16 + lr) * 128 + ((c * 4 + lg) ^ (lr & 7)) * 8];
                s[ks] = __builtin_amdgcn_mfma_f32_16x16x32_bf16(
                    __builtin_bit_cast(bf16x8, kf), __builtin_bit_cast(bf16x8, qf[c]),
                    s[ks], 0, 0, 0);
            }
        }
        __builtin_amdgcn_s_setprio(0);

        // lane-local row softmax over 16 values (+2 shfl_xor to combine lg-group)
        float mx0 = fmaxf(fmaxf(s[0][0], s[0][1]), fmaxf(s[0][2], s[0][3]));
        float mx1 = fmaxf(fmaxf(s[1][0], s[1][1]), fmaxf(s[1][2], s[1][3]));
        float mx2 = fmaxf(fmaxf(s[2][0], s[2][1]), fmaxf(s[2][2], s[2][3]));
        float mx3 = fmaxf(fmaxf(s[3][0], s[3][1]), fmaxf(s[3][2], s[3][3]));
        float pmax = fmaxf(fmaxf(mx0, mx1), fmaxf(mx2, mx3));
        pmax = fmaxf(pmax, __shfl_xor(pmax, 16));
        pmax = fmaxf(pmax, __shfl_xor(pmax, 32));
        bool need = pmax > m_run + 8.0f;         // defer-rescale (T13)
        float fac = need ? __expf(m_run - pmax) : 1.0f;
        float mn = need ? pmax : m_run;
        m_run = mn;

        float p[4][4], psum = 0.f;
#pragma unroll
        for (int ks = 0; ks < 4; ks++) {
            float q0e = __expf(s[ks][0] - mn), q1e = __expf(s[ks][1] - mn);
            float q2e = __expf(s[ks][2] - mn), q3e = __expf(s[ks][3] - mn);
            p[ks][0] = q0e; p[ks][1] = q1e; p[ks][2] = q2e; p[ks][3] = q3e;
            psum += (q0e + q1e) + (q2e + q3e);
        }
        psum += __shfl_xor(psum, 16);
        psum += __shfl_xor(psum, 32);
        l_run = l_run * fac + psum;

        // P -> LDS, involution swizzle chunk' = chunk ^ (lr&7) on 8-elem chunks
        unsigned short* pw = &Plds[w][0];
#pragma unroll
        for (int ks = 0; ks < 4; ks++) {
            ushort4 pk;
            pk.x = f2bf(p[ks][0]); pk.y = f2bf(p[ks][1]);
            pk.z = f2bf(p[ks][2]); pk.w = f2bf(p[ks][3]);
            int chunk = ks * 2 + (lg >> 1);
            *(ushort4*)&pw[lr * 64 + ((chunk ^ (lr & 7)) * 8) + (lg & 1) * 4] = pk;
        }

        if (__any((int)need)) {
            float facq[4];
#pragma unroll
            for (int r = 0; r < 4; r++) facq[r] = __shfl(fac, lg * 4 + r);
#pragma unroll
            for (int db = 0; db < 8; db++)
#pragma unroll
                for (int r = 0; r < 4; r++) acc[db][r] *= facq[r];
        }

        __builtin_amdgcn_s_setprio(1);
#pragma unroll
        for (int kk = 0; kk < 2; kk++) {
            i32x4 pf = *(const i32x4*)&pw[lr * 64 + ((kk * 4 + lg) ^ (lr & 7)) * 8];
#pragma unroll
            for (int db = 0; db < 8; db++) {
                i32x4 vf = *(const i32x4*)&Vlds[(db * 16 + lr) * 64 + ((kk * 4 + lg) ^ (lr & 7)) * 8];
                acc[db] = __builtin_amdgcn_mfma_f32_16x16x32_bf16(
                    __builtin_bit_cast(bf16x8, pf), __builtin_bit_cast(bf16x8, vf),
                    acc[db], 0, 0, 0);
            }
        }
        __builtin_amdgcn_s_setprio(0);
    }

    float inv[4];
#pragma unroll
    for (int r = 0; r < 4; r++) inv[r] = 1.0f / __shfl(l_run, lg * 4 + r);
#pragma unroll
    for (int db = 0; db < 8; db++)
#pragma unroll
        for (int r = 0; r < 4; r++) {
            int trow = q0 + w * 16 + lg * 4 + r;
            ctx[(size_t)(b * SEQ + trow) * HIDDEN + h * HDIM + db * 16 + lr] =
                f2bf(acc[db][r] * inv[r]);
        }
}

extern "C" void kernel_launch(void* const* d_in, const int* in_sizes, int n_in,
                              void* d_out, int out_size, void* d_ws, size_t ws_size,
                              hipStream_t stream)
{
    (void)in_sizes; (void)n_in; (void)out_size; (void)ws_size;
    const float* X  = (const float*)d_in[0];
    const float* Wq = (const float*)d_in[1];
    const float* Wk = (const float*)d_in[2];
    const float* Wv = (const float*)d_in[3];
    const float* Wo = (const float*)d_in[4];
    float* out = (float*)d_out;
    char* ws = (char*)d_ws;

    unsigned short* Xb  = (unsigned short*)(ws);                 // 16 MB  (4096x2048 bf16)
    unsigned short* WqT = (unsigned short*)(ws + 16777216);      // 8 MB each, N x K bf16
    unsigned short* WkT = (unsigned short*)(ws + 25165824);
    unsigned short* WvT = (unsigned short*)(ws + 33554432);
    unsigned short* WoT = (unsigned short*)(ws + 41943040);
    unsigned short* Qb  = (unsigned short*)(ws + 50331648);      // 16 MB each
    unsigned short* Kb  = (unsigned short*)(ws + 67108864);
    unsigned short* Vb  = (unsigned short*)(ws + 83886080);
    unsigned short* Vt  = (unsigned short*)(ws + 100663296);
    unsigned short* Cx  = (unsigned short*)(ws + 117440512);
    float* ctab = (float*)(ws + 134217728);                      // 0.5 MB each
    float* stab = (float*)(ws + 134742016);

    k_rope_tables<<<512, 256, 0, stream>>>(ctab, stab);
    k_cvt_bf16<<<8192, 256, 0, stream>>>(X, Xb, 2097152);
    k_transcvt<<<dim3(64, 64), dim3(32, 8), 0, stream>>>(Wq, WqT);
    k_transcvt<<<dim3(64, 64), dim3(32, 8), 0, stream>>>(Wk, WkT);
    k_transcvt<<<dim3(64, 64), dim3(32, 8), 0, stream>>>(Wv, WvT);
    k_transcvt<<<dim3(64, 64), dim3(32, 8), 0, stream>>>(Wo, WoT);
    k_gemm128<1><<<dim3(16, 32, 3), 256, 0, stream>>>(Xb, WqT, WkT, WvT,
                                                      Qb, Kb, Vb, 4096, 2048, 2048);
    k_rope<<<dim3(16384, 2), 256, 0, stream>>>(Qb, Kb, ctab, stab);
    k_vtrans<<<dim3(4, 64, 32), dim3(32, 8), 0, stream>>>(Vb, Vt);
    k_attn<<<dim3(32, 32), 256, 0, stream>>>(Qb, Kb, Vt, Cx);
    k_gemm128<0><<<dim3(16, 32, 1), 256, 0, stream>>>(Cx, WoT, WoT, WoT,
                                                      out, out, out, 4096, 2048, 2048);
}

// Round 5
// 350.034 us; speedup vs baseline: 1.4122x; 1.1141x over previous
//
#include <hip/hip_runtime.h>

#define HIDDEN 2048
#define SEQ    2048
#define BATCH  2
#define NHEAD  16
#define HDIM   128

typedef __attribute__((ext_vector_type(4))) int    i32x4;
typedef __attribute__((ext_vector_type(4))) float  f32x4;
typedef __attribute__((ext_vector_type(8))) __bf16 bf16x8;

__device__ __forceinline__ unsigned short f2bf(float f) {
    unsigned u = __builtin_bit_cast(unsigned, f);
    u += 0x7FFFu + ((u >> 16) & 1u);   // RNE (no NaN inputs in this pipeline)
    return (unsigned short)(u >> 16);
}
__device__ __forceinline__ float bf2f(unsigned short h) {
    unsigned u = ((unsigned)h) << 16;
    return __builtin_bit_cast(float, u);
}
// async global->LDS, 16B per lane; dest must be wave-uniform base + lane*16
__device__ __forceinline__ void gl_lds16(const unsigned short* g, unsigned short* l) {
    __builtin_amdgcn_global_load_lds(
        (const __attribute__((address_space(1))) unsigned int*)g,
        (__attribute__((address_space(3))) unsigned int*)l, 16, 0, 0);
}

// ---------------- RoPE tables: ctab/stab[t*64 + i] = cos/sin(t * 10000^(-i/64))
__global__ void k_rope_tables(float* __restrict__ ctab, float* __restrict__ stab) {
    int idx = blockIdx.x * 256 + threadIdx.x;      // exactly SEQ*64 threads
    int t = idx >> 6, i = idx & 63;
    float inv = expf(-(float)i * 0.14391156831212793f);  // ln(10000)/64
    float ang = (float)t * inv;
    ctab[idx] = cosf(ang);
    stab[idx] = sinf(ang);
}

// ---------------- fp32 -> bf16 convert (4 elems/thread)
__global__ void k_cvt_bf16(const float* __restrict__ in, unsigned short* __restrict__ out, int n4) {
    int idx = blockIdx.x * blockDim.x + threadIdx.x;
    if (idx < n4) {
        float4 v = ((const float4*)in)[idx];
        ushort4 o;
        o.x = f2bf(v.x); o.y = f2bf(v.y); o.z = f2bf(v.z); o.w = f2bf(v.w);
        ((ushort4*)out)[idx] = o;
    }
}

// ---------------- W (K x N fp32) -> W^T (N x K bf16), 32x32 LDS tiles
__global__ void k_transcvt(const float* __restrict__ in, unsigned short* __restrict__ out) {
    __shared__ float tile[32][33];
    int tx = threadIdx.x, ty = threadIdx.y;
    int x = blockIdx.x * 32 + tx, y0 = blockIdx.y * 32;
#pragma unroll
    for (int i = 0; i < 4; i++)
        tile[ty + i * 8][tx] = in[(size_t)(y0 + ty + i * 8) * HIDDEN + x];
    __syncthreads();
    int x2 = blockIdx.y * 32 + tx, y2 = blockIdx.x * 32;
#pragma unroll
    for (int i = 0; i < 4; i++)
        out[(size_t)(y2 + ty + i * 8) * HIDDEN + x2] = f2bf(tile[tx][ty + i * 8]);
}

// ---------------- 256x128-tile bf16 GEMM, triple-buffer LDS, counted vmcnt(6)
// pipeline: iter t = { vmcnt(6); barrier; issue loads(t+2); ds_read(t); 32 MFMA }
// tile t's 6 loads certified by vmcnt(6) (t+1's 6 stay in flight across barrier);
// buf[(t+2)%3] overwrites tile t-1 whose reads finished before this barrier.
// T2 involution swizzle k8^=(row&7) on global source AND ds_read (rule 21).
template <int OUTB>
__global__ __launch_bounds__(512, 1) void k_gemm256(
    const unsigned short* __restrict__ A,
    const unsigned short* __restrict__ B0, const unsigned short* __restrict__ B1,
    const unsigned short* __restrict__ B2,
    void* __restrict__ C0, void* __restrict__ C1, void* __restrict__ C2,
    int K)
{
    __shared__ __align__(16) unsigned short S[3 * 24576];   // 144 KB
    const int nwg = gridDim.x;                               // 768 or 256, %8==0
    int id = blockIdx.x;
    int wg = (id & 7) * (nwg >> 3) + (id >> 3);              // XCD-aware swizzle (T1)
    const int z = wg >> 8;                                   // 16x16 blocks per z
    const int my = (wg >> 4) & 15, nx = wg & 15;
    const unsigned short* Bm = (z == 0) ? B0 : (z == 1 ? B1 : B2);
    void* Cv = (z == 0) ? C0 : (z == 1 ? C1 : C2);
    const int m0 = my * 256, n0 = nx * 128;
    const int tid = threadIdx.x, l = tid & 63, w = tid >> 6;
    const int wm = w >> 1, wn = w & 1;                       // 4 M-waves x 2 N-waves
    const int lr = l & 15, lg = l >> 4;

    // per-thread staging: 4 A-chunks + 2 B-chunks, 16B each, source pre-swizzled.
    // LDS dest offset = 16B*tid + const  (wave-uniform base + lane*16: required)
    const unsigned short* sg[6];
    int so[6];
#pragma unroll
    for (int j = 0; j < 4; j++) {
        int c = tid + j * 512, row = c >> 3, k8 = c & 7;
        sg[j] = A + (size_t)(m0 + row) * K + ((k8 ^ (row & 7)) * 8);
        so[j] = row * 64 + k8 * 8;
    }
#pragma unroll
    for (int j = 0; j < 2; j++) {
        int c = tid + j * 512, row = c >> 3, k8 = c & 7;
        sg[4 + j] = Bm + (size_t)(n0 + row) * K + ((k8 ^ (row & 7)) * 8);
        so[4 + j] = 16384 + row * 64 + k8 * 8;
    }

    f32x4 acc[4][4] = {};

    auto stage = [&](int t) {
        unsigned short* buf = &S[(t % 3) * 24576];
        const int ko = t * 64;
#pragma unroll
        for (int j = 0; j < 6; j++) gl_lds16(sg[j] + ko, &buf[so[j]]);
    };
    auto compute = [&](int t) {
        const unsigned short* buf = &S[(t % 3) * 24576];
        const unsigned short* bb = buf + 16384;
        const int xk0 = (lg ^ (lr & 7)) * 8, xk1 = ((4 + lg) ^ (lr & 7)) * 8;
        i32x4 af0[4], af1[4], bf0[4], bf1[4];
#pragma unroll
        for (int i = 0; i < 4; i++) {
            int R = (wm * 64 + i * 16 + lr) * 64;
            af0[i] = *(const i32x4*)&buf[R + xk0];
            af1[i] = *(const i32x4*)&buf[R + xk1];
        }
#pragma unroll
        for (int j = 0; j < 4; j++) {
            int R = (wn * 64 + j * 16 + lr) * 64;
            bf0[j] = *(const i32x4*)&bb[R + xk0];
            bf1[j] = *(const i32x4*)&bb[R + xk1];
        }
        __builtin_amdgcn_s_setprio(1);
#pragma unroll
        for (int i = 0; i < 4; i++)
#pragma unroll
            for (int j = 0; j < 4; j++)
                acc[i][j] = __builtin_amdgcn_mfma_f32_16x16x32_bf16(
                    __builtin_bit_cast(bf16x8, af0[i]),
                    __builtin_bit_cast(bf16x8, bf0[j]), acc[i][j], 0, 0, 0);
#pragma unroll
        for (int i = 0; i < 4; i++)
#pragma unroll
            for (int j = 0; j < 4; j++)
                acc[i][j] = __builtin_amdgcn_mfma_f32_16x16x32_bf16(
                    __builtin_bit_cast(bf16x8, af1[i]),
                    __builtin_bit_cast(bf16x8, bf1[j]), acc[i][j], 0, 0, 0);
        __builtin_amdgcn_s_setprio(0);
    };

    const int nt = K / 64;                 // 32
    stage(0); stage(1);                    // 12 loads in flight
    for (int t = 0; t < nt - 1; ++t) {
        asm volatile("s_waitcnt vmcnt(6)" ::: "memory");
        __builtin_amdgcn_s_barrier();
        __builtin_amdgcn_sched_barrier(0);
        if (t < nt - 2) stage(t + 2);
        compute(t);
    }
    asm volatile("s_waitcnt vmcnt(0)" ::: "memory");
    __builtin_amdgcn_s_barrier();
    __builtin_amdgcn_sched_barrier(0);
    compute(nt - 1);

#pragma unroll
    for (int i = 0; i < 4; i++)
#pragma unroll
        for (int j = 0; j < 4; j++)
#pragma unroll
            for (int r = 0; r < 4; r++) {
                int m = m0 + wm * 64 + i * 16 + lg * 4 + r;
                int n = n0 + wn * 64 + j * 16 + lr;
                float v = acc[i][j][r];
                if (OUTB) ((unsigned short*)Cv)[(size_t)m * 2048 + n] = f2bf(v);
                else      ((float*)Cv)[(size_t)m * 2048 + n] = v;
            }
}

// ---------------- RoPE in-place on Q,K; Q additionally scaled by 1/sqrt(D)
__global__ void k_rope(unsigned short* __restrict__ Q, unsigned short* __restrict__ Kb,
                       const float* __restrict__ ctab, const float* __restrict__ stab)
{
    const int tid = threadIdx.x, l = tid & 63, w = tid >> 6;
    int hr = blockIdx.x * 4 + w;                 // head-row id, one wave each
    unsigned short* X = blockIdx.y ? Kb : Q;
    float sc = blockIdx.y ? 1.0f : 0.08838834764831845f;   // 1/sqrt(128) folded into Q
    int bt = hr >> 4, h = hr & 15, t = bt & (SEQ - 1);
    size_t base = (size_t)bt * HIDDEN + h * HDIM;
    int d0 = l * 2;
    ushort2 xv = *(const ushort2*)&X[base + d0];
    float x0 = bf2f(xv.x), x1 = bf2f(xv.y);
    float prev = __shfl(x1, (l + 63) & 63);      // x[d0-1], lane0 wraps to x[127]
    int i0 = d0 & 63, i1 = (d0 + 1) & 63;
    float c0 = ctab[t * 64 + i0], s0 = stab[t * 64 + i0];
    float c1 = ctab[t * 64 + i1], s1 = stab[t * 64 + i1];
    ushort2 ov;
    ov.x = f2bf((x0 * c0 + prev * s0) * sc);
    ov.y = f2bf((x1 * c1 + x0 * s1) * sc);
    *(ushort2*)&X[base + d0] = ov;
}

// ---------------- V[bt][h*128+d] -> Vt[bh][d][t]  (per-(b,h) transpose)
__global__ void k_vtrans(const unsigned short* __restrict__ V, unsigned short* __restrict__ Vt)
{
    __shared__ unsigned short tile[32][33];
    int z = blockIdx.z;                     // bh
    int b = z >> 4, h = z & 15;
    int tx = threadIdx.x, ty = threadIdx.y;
    int d0 = blockIdx.x * 32, t0 = blockIdx.y * 32;
    const size_t ibase = (size_t)b * SEQ * HIDDEN + h * HDIM;
#pragma unroll
    for (int i = 0; i < 4; i++)
        tile[ty + i * 8][tx] = V[ibase + (size_t)(t0 + ty + i * 8) * HIDDEN + d0 + tx];
    __syncthreads();
    const size_t obase = (size_t)z * HDIM * SEQ;
#pragma unroll
    for (int i = 0; i < 4; i++)
        Vt[obase + (size_t)(d0 + ty + i * 8) * SEQ + t0 + tx] = tile[tx][ty + i * 8];
}

// ---------------- flash attention, swapped-QK^T (T12 structure adaptation)
__global__ __launch_bounds__(256) void k_attn(
    const unsigned short* __restrict__ Q, const unsigned short* __restrict__ K,
    const unsigned short* __restrict__ Vt, unsigned short* __restrict__ ctx)
{
    __shared__ __align__(16) unsigned short Klds[64 * 128];
    __shared__ __align__(16) unsigned short Vlds[128 * 64];
    __shared__ __align__(16) unsigned short Plds[4][16 * 64];
    const int tid = threadIdx.x, l = tid & 63, w = tid >> 6;
    const int lr = l & 15, lg = l >> 4;
    const int q0 = blockIdx.x * 64;
    const int bh = blockIdx.y, b = bh >> 4, h = bh & 15;

    const int qrow = q0 + w * 16 + lr;
    const unsigned short* qbase = Q + (size_t)(b * SEQ + qrow) * HIDDEN + h * HDIM + lg * 8;
    i32x4 qf[4];
#pragma unroll
    for (int c = 0; c < 4; c++) qf[c] = *(const i32x4*)(qbase + c * 32);

    // staging pointers: 4 K-chunks + 4 V-chunks per thread, source pre-swizzled
    const unsigned short* kg[4];
    const unsigned short* vg[4];
    int kl[4], vl[4];
#pragma unroll
    for (int c = 0; c < 4; c++) {
        int cc = tid + c * 256;
        {   int row = cc >> 4, ch = cc & 15, sch = ch ^ (row & 7);
            kg[c] = K + (size_t)(b * SEQ + row) * HIDDEN + h * HDIM + sch * 8;
            kl[c] = cc * 8; }
        {   int row = cc >> 3, ch = cc & 7, sch = ch ^ (row & 7);
            vg[c] = Vt + (size_t)(bh * HDIM + row) * SEQ + sch * 8;
            vl[c] = cc * 8; }
    }

    f32x4 acc[8] = {};
    float m_run = -1e30f, l_run = 0.f;      // per-lane stats for q-row q0+w*16+lr

    for (int t0 = 0; t0 < SEQ; t0 += 64) {
        __syncthreads();
#pragma unroll
        for (int c = 0; c < 4; c++) {
            gl_lds16(kg[c], &Klds[kl[c]]);  kg[c] += 64 * HIDDEN;
            gl_lds16(vg[c], &Vlds[vl[c]]);  vg[c] += 64;
        }
        __syncthreads();

        // swapped QK^T: mfma(K,Q) -> lane(lr,lg) reg r = S[q=lr][kv=slice*16+lg*4+r]
        f32x4 s[4];
        __builtin_amdgcn_s_setprio(1);
#pragma unroll
        for (int ks = 0; ks < 4; ks++) {
            s[ks] = f32x4{0.f, 0.f, 0.f, 0.f};
#pragma unroll
            for (int c = 0; c < 4; c++) {
                i32x4 kf = *(const i32x4*)&Klds[(ks * 16 + lr) * 128 + ((c * 4 + lg) ^ (lr & 7)) * 8];
                s[ks] = __builtin_amdgcn_mfma_f32_16x16x32_bf16(
                    __builtin_bit_cast(bf16x8, kf), __builtin_bit_cast(bf16x8, qf[c]),
                    s[ks], 0, 0, 0);
            }
        }
        __builtin_amdgcn_s_setprio(0);

        // lane-local row softmax over 16 values (+2 shfl_xor to combine lg-group)
        float mx0 = fmaxf(fmaxf(s[0][0], s[0][1]), fmaxf(s[0][2], s[0][3]));
        float mx1 = fmaxf(fmaxf(s[1][0], s[1][1]), fmaxf(s[1][2], s[1][3]));
        float mx2 = fmaxf(fmaxf(s[2][0], s[2][1]), fmaxf(s[2][2], s[2][3]));
        float mx3 = fmaxf(fmaxf(s[3][0], s[3][1]), fmaxf(s[3][2], s[3][3]));
        float pmax = fmaxf(fmaxf(mx0, mx1), fmaxf(mx2, mx3));
        pmax = fmaxf(pmax, __shfl_xor(pmax, 16));
        pmax = fmaxf(pmax, __shfl_xor(pmax, 32));
        bool need = pmax > m_run + 8.0f;         // defer-rescale (T13)
        float fac = need ? __expf(m_run - pmax) : 1.0f;
        float mn = need ? pmax : m_run;
        m_run = mn;

        float p[4][4], psum = 0.f;
#pragma unroll
        for (int ks = 0; ks < 4; ks++) {
            float q0e = __expf(s[ks][0] - mn), q1e = __expf(s[ks][1] - mn);
            float q2e = __expf(s[ks][2] - mn), q3e = __expf(s[ks][3] - mn);
            p[ks][0] = q0e; p[ks][1] = q1e; p[ks][2] = q2e; p[ks][3] = q3e;
            psum += (q0e + q1e) + (q2e + q3e);
        }
        psum += __shfl_xor(psum, 16);
        psum += __shfl_xor(psum, 32);
        l_run = l_run * fac + psum;

        // P -> LDS, involution swizzle chunk' = chunk ^ (lr&7) on 8-elem chunks
        unsigned short* pw = &Plds[w][0];
#pragma unroll
        for (int ks = 0; ks < 4; ks++) {
            ushort4 pk;
            pk.x = f2bf(p[ks][0]); pk.y = f2bf(p[ks][1]);
            pk.z = f2bf(p[ks][2]); pk.w = f2bf(p[ks][3]);
            int chunk = ks * 2 + (lg >> 1);
            *(ushort4*)&pw[lr * 64 + ((chunk ^ (lr & 7)) * 8) + (lg & 1) * 4] = pk;
        }

        if (__any((int)need)) {
            float facq[4];
#pragma unroll
            for (int r = 0; r < 4; r++) facq[r] = __shfl(fac, lg * 4 + r);
#pragma unroll
            for (int db = 0; db < 8; db++)
#pragma unroll
                for (int r = 0; r < 4; r++) acc[db][r] *= facq[r];
        }

        __builtin_amdgcn_s_setprio(1);
#pragma unroll
        for (int kk = 0; kk < 2; kk++) {
            i32x4 pf = *(const i32x4*)&pw[lr * 64 + ((kk * 4 + lg) ^ (lr & 7)) * 8];
#pragma unroll
            for (int db = 0; db < 8; db++) {
                i32x4 vf = *(const i32x4*)&Vlds[(db * 16 + lr) * 64 + ((kk * 4 + lg) ^ (lr & 7)) * 8];
                acc[db] = __builtin_amdgcn_mfma_f32_16x16x32_bf16(
                    __builtin_bit_cast(bf16x8, pf), __builtin_bit_cast(bf16x8, vf),
                    acc[db], 0, 0, 0);
            }
        }
        __builtin_amdgcn_s_setprio(0);
    }

    float inv[4];
#pragma unroll
    for (int r = 0; r < 4; r++) inv[r] = 1.0f / __shfl(l_run, lg * 4 + r);
#pragma unroll
    for (int db = 0; db < 8; db++)
#pragma unroll
        for (int r = 0; r < 4; r++) {
            int trow = q0 + w * 16 + lg * 4 + r;
            ctx[(size_t)(b * SEQ + trow) * HIDDEN + h * HDIM + db * 16 + lr] =
                f2bf(acc[db][r] * inv[r]);
        }
}

extern "C" void kernel_launch(void* const* d_in, const int* in_sizes, int n_in,
                              void* d_out, int out_size, void* d_ws, size_t ws_size,
                              hipStream_t stream)
{
    (void)in_sizes; (void)n_in; (void)out_size; (void)ws_size;
    const float* X  = (const float*)d_in[0];
    const float* Wq = (const float*)d_in[1];
    const float* Wk = (const float*)d_in[2];
    const float* Wv = (const float*)d_in[3];
    const float* Wo = (const float*)d_in[4];
    float* out = (float*)d_out;
    char* ws = (char*)d_ws;

    unsigned short* Xb  = (unsigned short*)(ws);                 // 16 MB  (4096x2048 bf16)
    unsigned short* WqT = (unsigned short*)(ws + 16777216);      // 8 MB each, N x K bf16
    unsigned short* WkT = (unsigned short*)(ws + 25165824);
    unsigned short* WvT = (unsigned short*)(ws + 33554432);
    unsigned short* WoT = (unsigned short*)(ws + 41943040);
    unsigned short* Qb  = (unsigned short*)(ws + 50331648);      // 16 MB each
    unsigned short* Kb  = (unsigned short*)(ws + 67108864);
    unsigned short* Vb  = (unsigned short*)(ws + 83886080);
    unsigned short* Vt  = (unsigned short*)(ws + 100663296);
    unsigned short* Cx  = (unsigned short*)(ws + 117440512);
    float* ctab = (float*)(ws + 134217728);                      // 0.5 MB each
    float* stab = (float*)(ws + 134742016);

    k_rope_tables<<<512, 256, 0, stream>>>(ctab, stab);
    k_cvt_bf16<<<8192, 256, 0, stream>>>(X, Xb, 2097152);
    k_transcvt<<<dim3(64, 64), dim3(32, 8), 0, stream>>>(Wq, WqT);
    k_transcvt<<<dim3(64, 64), dim3(32, 8), 0, stream>>>(Wk, WkT);
    k_transcvt<<<dim3(64, 64), dim3(32, 8), 0, stream>>>(Wv, WvT);
    k_transcvt<<<dim3(64, 64), dim3(32, 8), 0, stream>>>(Wo, WoT);
    k_gemm256<1><<<768, 512, 0, stream>>>(Xb, WqT, WkT, WvT, Qb, Kb, Vb, 2048);
    k_rope<<<dim3(16384, 2), 256, 0, stream>>>(Qb, Kb, ctab, stab);
    k_vtrans<<<dim3(4, 64, 32), dim3(32, 8), 0, stream>>>(Vb, Vt);
    k_attn<<<dim3(32, 32), 256, 0, stream>>>(Qb, Kb, Vt, Cx);
    k_gemm256<0><<<256, 512, 0, stream>>>(Cx, WoT, WoT, WoT, out, out, out, 2048);
}

// Round 6
// 332.596 us; speedup vs baseline: 1.4863x; 1.0524x over previous
//
#include <hip/hip_runtime.h>

#define HIDDEN 2048
#define SEQ    2048
#define BATCH  2
#define NHEAD  16
#define HDIM   128

typedef __attribute__((ext_vector_type(4))) int    i32x4;
typedef __attribute__((ext_vector_type(4))) float  f32x4;
typedef __attribute__((ext_vector_type(8))) __bf16 bf16x8;

__device__ __forceinline__ unsigned short f2bf(float f) {
    return __builtin_bit_cast(unsigned short, (__bf16)f);   // hw RNE cvt
}
__device__ __forceinline__ float bf2f(unsigned short h) {
    unsigned u = ((unsigned)h) << 16;
    return __builtin_bit_cast(float, u);
}
// async global->LDS, 16B per lane; dest must be wave-uniform base + lane*16
__device__ __forceinline__ void gl_lds16(const unsigned short* g, unsigned short* l) {
    __builtin_amdgcn_global_load_lds(
        (const __attribute__((address_space(1))) unsigned int*)g,
        (__attribute__((address_space(3))) unsigned int*)l, 16, 0, 0);
}

// ---------------- RoPE tables: ctab/stab[t*64 + i] = cos/sin(t * 10000^(-i/64))
__global__ void k_rope_tables(float* __restrict__ ctab, float* __restrict__ stab) {
    int idx = blockIdx.x * 256 + threadIdx.x;      // exactly SEQ*64 threads
    int t = idx >> 6, i = idx & 63;
    float inv = expf(-(float)i * 0.14391156831212793f);  // ln(10000)/64
    float ang = (float)t * inv;
    ctab[idx] = cosf(ang);
    stab[idx] = sinf(ang);
}

// ---------------- fp32 -> bf16 convert (4 elems/thread)
__global__ void k_cvt_bf16(const float* __restrict__ in, unsigned short* __restrict__ out, int n4) {
    int idx = blockIdx.x * blockDim.x + threadIdx.x;
    if (idx < n4) {
        float4 v = ((const float4*)in)[idx];
        ushort4 o;
        o.x = f2bf(v.x); o.y = f2bf(v.y); o.z = f2bf(v.z); o.w = f2bf(v.w);
        ((ushort4*)out)[idx] = o;
    }
}

// ---------------- W (K x N fp32) -> W^T (N x K bf16), 32x32 LDS tiles
__global__ void k_transcvt(const float* __restrict__ in, unsigned short* __restrict__ out) {
    __shared__ float tile[32][33];
    int tx = threadIdx.x, ty = threadIdx.y;
    int x = blockIdx.x * 32 + tx, y0 = blockIdx.y * 32;
#pragma unroll
    for (int i = 0; i < 4; i++)
        tile[ty + i * 8][tx] = in[(size_t)(y0 + ty + i * 8) * HIDDEN + x];
    __syncthreads();
    int x2 = blockIdx.y * 32 + tx, y2 = blockIdx.x * 32;
#pragma unroll
    for (int i = 0; i < 4; i++)
        out[(size_t)(y2 + ty + i * 8) * HIDDEN + x2] = f2bf(tile[tx][ty + i * 8]);
}

// ---------------- 256x128-tile bf16 GEMM, triple-buffer LDS, counted vmcnt(6)
template <int OUTB>
__global__ __launch_bounds__(512, 1) void k_gemm256(
    const unsigned short* __restrict__ A,
    const unsigned short* __restrict__ B0, const unsigned short* __restrict__ B1,
    const unsigned short* __restrict__ B2,
    void* __restrict__ C0, void* __restrict__ C1, void* __restrict__ C2,
    int K)
{
    __shared__ __align__(16) unsigned short S[3 * 24576];   // 144 KB
    const int nwg = gridDim.x;                               // 768 or 256, %8==0
    int id = blockIdx.x;
    int wg = (id & 7) * (nwg >> 3) + (id >> 3);              // XCD-aware swizzle (T1)
    const int z = wg >> 8;                                   // 16x16 blocks per z
    const int my = (wg >> 4) & 15, nx = wg & 15;
    const unsigned short* Bm = (z == 0) ? B0 : (z == 1 ? B1 : B2);
    void* Cv = (z == 0) ? C0 : (z == 1 ? C1 : C2);
    const int m0 = my * 256, n0 = nx * 128;
    const int tid = threadIdx.x, l = tid & 63, w = tid >> 6;
    const int wm = w >> 1, wn = w & 1;                       // 4 M-waves x 2 N-waves
    const int lr = l & 15, lg = l >> 4;

    const unsigned short* sg[6];
    int so[6];
#pragma unroll
    for (int j = 0; j < 4; j++) {
        int c = tid + j * 512, row = c >> 3, k8 = c & 7;
        sg[j] = A + (size_t)(m0 + row) * K + ((k8 ^ (row & 7)) * 8);
        so[j] = row * 64 + k8 * 8;
    }
#pragma unroll
    for (int j = 0; j < 2; j++) {
        int c = tid + j * 512, row = c >> 3, k8 = c & 7;
        sg[4 + j] = Bm + (size_t)(n0 + row) * K + ((k8 ^ (row & 7)) * 8);
        so[4 + j] = 16384 + row * 64 + k8 * 8;
    }

    f32x4 acc[4][4] = {};

    auto stage = [&](int t) {
        unsigned short* buf = &S[(t % 3) * 24576];
        const int ko = t * 64;
#pragma unroll
        for (int j = 0; j < 6; j++) gl_lds16(sg[j] + ko, &buf[so[j]]);
    };
    auto compute = [&](int t) {
        const unsigned short* buf = &S[(t % 3) * 24576];
        const unsigned short* bb = buf + 16384;
        const int xk0 = (lg ^ (lr & 7)) * 8, xk1 = ((4 + lg) ^ (lr & 7)) * 8;
        i32x4 af0[4], af1[4], bf0[4], bf1[4];
#pragma unroll
        for (int i = 0; i < 4; i++) {
            int R = (wm * 64 + i * 16 + lr) * 64;
            af0[i] = *(const i32x4*)&buf[R + xk0];
            af1[i] = *(const i32x4*)&buf[R + xk1];
        }
#pragma unroll
        for (int j = 0; j < 4; j++) {
            int R = (wn * 64 + j * 16 + lr) * 64;
            bf0[j] = *(const i32x4*)&bb[R + xk0];
            bf1[j] = *(const i32x4*)&bb[R + xk1];
        }
        __builtin_amdgcn_s_setprio(1);
#pragma unroll
        for (int i = 0; i < 4; i++)
#pragma unroll
            for (int j = 0; j < 4; j++)
                acc[i][j] = __builtin_amdgcn_mfma_f32_16x16x32_bf16(
                    __builtin_bit_cast(bf16x8, af0[i]),
                    __builtin_bit_cast(bf16x8, bf0[j]), acc[i][j], 0, 0, 0);
#pragma unroll
        for (int i = 0; i < 4; i++)
#pragma unroll
            for (int j = 0; j < 4; j++)
                acc[i][j] = __builtin_amdgcn_mfma_f32_16x16x32_bf16(
                    __builtin_bit_cast(bf16x8, af1[i]),
                    __builtin_bit_cast(bf16x8, bf1[j]), acc[i][j], 0, 0, 0);
        __builtin_amdgcn_s_setprio(0);
    };

    const int nt = K / 64;                 // 32
    stage(0); stage(1);                    // 12 loads in flight
    for (int t = 0; t < nt - 1; ++t) {
        asm volatile("s_waitcnt vmcnt(6)" ::: "memory");
        __builtin_amdgcn_s_barrier();
        __builtin_amdgcn_sched_barrier(0);
        if (t < nt - 2) stage(t + 2);
        compute(t);
    }
    asm volatile("s_waitcnt vmcnt(0)" ::: "memory");
    __builtin_amdgcn_s_barrier();
    __builtin_amdgcn_sched_barrier(0);
    compute(nt - 1);

#pragma unroll
    for (int i = 0; i < 4; i++)
#pragma unroll
        for (int j = 0; j < 4; j++)
#pragma unroll
            for (int r = 0; r < 4; r++) {
                int m = m0 + wm * 64 + i * 16 + lg * 4 + r;
                int n = n0 + wn * 64 + j * 16 + lr;
                float v = acc[i][j][r];
                if (OUTB) ((unsigned short*)Cv)[(size_t)m * 2048 + n] = f2bf(v);
                else      ((float*)Cv)[(size_t)m * 2048 + n] = v;
            }
}

// ---------------- RoPE in-place on Q,K; Q scaled by log2(e)/sqrt(D) (exp2-domain)
__global__ void k_rope(unsigned short* __restrict__ Q, unsigned short* __restrict__ Kb,
                       const float* __restrict__ ctab, const float* __restrict__ stab)
{
    const int tid = threadIdx.x, l = tid & 63, w = tid >> 6;
    int hr = blockIdx.x * 4 + w;                 // head-row id, one wave each
    unsigned short* X = blockIdx.y ? Kb : Q;
    float sc = blockIdx.y ? 1.0f : 0.12751743f;  // log2(e)/sqrt(128) folded into Q
    int bt = hr >> 4, h = hr & 15, t = bt & (SEQ - 1);
    size_t base = (size_t)bt * HIDDEN + h * HDIM;
    int d0 = l * 2;
    ushort2 xv = *(const ushort2*)&X[base + d0];
    float x0 = bf2f(xv.x), x1 = bf2f(xv.y);
    float prev = __shfl(x1, (l + 63) & 63);      // x[d0-1], lane0 wraps to x[127]
    int i0 = d0 & 63, i1 = (d0 + 1) & 63;
    float c0 = ctab[t * 64 + i0], s0 = stab[t * 64 + i0];
    float c1 = ctab[t * 64 + i1], s1 = stab[t * 64 + i1];
    ushort2 ov;
    ov.x = f2bf((x0 * c0 + prev * s0) * sc);
    ov.y = f2bf((x1 * c1 + x0 * s1) * sc);
    *(ushort2*)&X[base + d0] = ov;
}

// ---------------- V[bt][h*128+d] -> Vt[bh][d][t]  (per-(b,h) transpose)
__global__ void k_vtrans(const unsigned short* __restrict__ V, unsigned short* __restrict__ Vt)
{
    __shared__ unsigned short tile[32][33];
    int z = blockIdx.z;                     // bh
    int b = z >> 4, h = z & 15;
    int tx = threadIdx.x, ty = threadIdx.y;
    int d0 = blockIdx.x * 32, t0 = blockIdx.y * 32;
    const size_t ibase = (size_t)b * SEQ * HIDDEN + h * HDIM;
#pragma unroll
    for (int i = 0; i < 4; i++)
        tile[ty + i * 8][tx] = V[ibase + (size_t)(t0 + ty + i * 8) * HIDDEN + d0 + tx];
    __syncthreads();
    const size_t obase = (size_t)z * HDIM * SEQ;
#pragma unroll
    for (int i = 0; i < 4; i++)
        Vt[obase + (size_t)(d0 + ty + i * 8) * SEQ + t0 + tx] = tile[tx][ty + i * 8];
}

// ---------------- flash attention, swapped-QK^T + K/V double-buffer pipeline
// iter t: vmcnt(0) certifies tile t (issued last iter, latency hidden under
// compute(t-1)); barrier; issue stage(t+1) into buf[(t+1)&1] (held tile t-1,
// all reads pre-barrier); compute tile t. exp2-domain softmax.
__global__ __launch_bounds__(256) void k_attn(
    const unsigned short* __restrict__ Q, const unsigned short* __restrict__ K,
    const unsigned short* __restrict__ Vt, unsigned short* __restrict__ ctx)
{
    __shared__ __align__(16) unsigned short Klds[2][64 * 128];
    __shared__ __align__(16) unsigned short Vlds[2][128 * 64];
    __shared__ __align__(16) unsigned short Plds[4][16 * 64];
    const int tid = threadIdx.x, l = tid & 63, w = tid >> 6;
    const int lr = l & 15, lg = l >> 4;
    const int q0 = blockIdx.x * 64;
    const int bh = blockIdx.y, b = bh >> 4, h = bh & 15;

    const int qrow = q0 + w * 16 + lr;
    const unsigned short* qbase = Q + (size_t)(b * SEQ + qrow) * HIDDEN + h * HDIM + lg * 8;
    i32x4 qf[4];
#pragma unroll
    for (int c = 0; c < 4; c++) qf[c] = *(const i32x4*)(qbase + c * 32);

    // staging: 4 K-chunks + 4 V-chunks per thread, source pre-swizzled (rule 21)
    const unsigned short* kg[4];
    const unsigned short* vg[4];
    int kl[4], vl[4];
#pragma unroll
    for (int c = 0; c < 4; c++) {
        int cc = tid + c * 256;
        {   int row = cc >> 4, ch = cc & 15, sch = ch ^ (row & 7);
            kg[c] = K + (size_t)(b * SEQ + row) * HIDDEN + h * HDIM + sch * 8;
            kl[c] = cc * 8; }
        {   int row = cc >> 3, ch = cc & 7, sch = ch ^ (row & 7);
            vg[c] = Vt + (size_t)(bh * HDIM + row) * SEQ + sch * 8;
            vl[c] = cc * 8; }
    }

    auto stage = [&](int t, int bsel) {
        const size_t ko = (size_t)t * 64;
#pragma unroll
        for (int c = 0; c < 4; c++) {
            gl_lds16(kg[c] + ko * HIDDEN, &Klds[bsel][kl[c]]);
            gl_lds16(vg[c] + ko,          &Vlds[bsel][vl[c]]);
        }
    };

    f32x4 acc[8] = {};
    float m_run = -1e30f, l_run = 0.f;      // per-lane stats for q-row q0+w*16+lr

    stage(0, 0);
    const int nt = SEQ / 64;                // 32
    for (int t = 0; t < nt; ++t) {
        asm volatile("s_waitcnt vmcnt(0)" ::: "memory");
        __builtin_amdgcn_s_barrier();
        asm volatile("" ::: "memory");
        __builtin_amdgcn_sched_barrier(0);
        if (t + 1 < nt) stage(t + 1, (t + 1) & 1);
        const unsigned short* Kb_ = Klds[t & 1];
        const unsigned short* Vb_ = Vlds[t & 1];

        // swapped QK^T: mfma(K,Q) -> lane(lr,lg) reg r = S[q=lr][kv=ks*16+lg*4+r]
        f32x4 s[4];
        __builtin_amdgcn_s_setprio(1);
#pragma unroll
        for (int ks = 0; ks < 4; ks++) {
            s[ks] = f32x4{0.f, 0.f, 0.f, 0.f};
#pragma unroll
            for (int c = 0; c < 4; c++) {
                i32x4 kf = *(const i32x4*)&Kb_[(ks * 16 + lr) * 128 + ((c * 4 + lg) ^ (lr & 7)) * 8];
                s[ks] = __builtin_amdgcn_mfma_f32_16x16x32_bf16(
                    __builtin_bit_cast(bf16x8, kf), __builtin_bit_cast(bf16x8, qf[c]),
                    s[ks], 0, 0, 0);
            }
        }
        __builtin_amdgcn_s_setprio(0);

        // lane-local row softmax (exp2 domain; scores pre-scaled by log2e/sqrt(D))
        float mx0 = fmaxf(fmaxf(s[0][0], s[0][1]), fmaxf(s[0][2], s[0][3]));
        float mx1 = fmaxf(fmaxf(s[1][0], s[1][1]), fmaxf(s[1][2], s[1][3]));
        float mx2 = fmaxf(fmaxf(s[2][0], s[2][1]), fmaxf(s[2][2], s[2][3]));
        float mx3 = fmaxf(fmaxf(s[3][0], s[3][1]), fmaxf(s[3][2], s[3][3]));
        float pmax = fmaxf(fmaxf(mx0, mx1), fmaxf(mx2, mx3));
        pmax = fmaxf(pmax, __shfl_xor(pmax, 16));
        pmax = fmaxf(pmax, __shfl_xor(pmax, 32));
        bool need = pmax > m_run + 8.0f;         // defer-rescale (T13), P <= 2^8
        float fac = need ? __builtin_amdgcn_exp2f(m_run - pmax) : 1.0f;
        float mn = need ? pmax : m_run;
        m_run = mn;

        float p[4][4], psum = 0.f;
#pragma unroll
        for (int ks = 0; ks < 4; ks++) {
            float e0 = __builtin_amdgcn_exp2f(s[ks][0] - mn);
            float e1 = __builtin_amdgcn_exp2f(s[ks][1] - mn);
            float e2 = __builtin_amdgcn_exp2f(s[ks][2] - mn);
            float e3 = __builtin_amdgcn_exp2f(s[ks][3] - mn);
            p[ks][0] = e0; p[ks][1] = e1; p[ks][2] = e2; p[ks][3] = e3;
            psum += (e0 + e1) + (e2 + e3);
        }
        psum += __shfl_xor(psum, 16);
        psum += __shfl_xor(psum, 32);
        l_run = l_run * fac + psum;

        // P -> LDS, involution swizzle chunk' = chunk ^ (lr&7) on 8-elem chunks
        unsigned short* pw = &Plds[w][0];
#pragma unroll
        for (int ks = 0; ks < 4; ks++) {
            ushort4 pk;
            pk.x = f2bf(p[ks][0]); pk.y = f2bf(p[ks][1]);
            pk.z = f2bf(p[ks][2]); pk.w = f2bf(p[ks][3]);
            int chunk = ks * 2 + (lg >> 1);
            *(ushort4*)&pw[lr * 64 + ((chunk ^ (lr & 7)) * 8) + (lg & 1) * 4] = pk;
        }

        if (__any((int)need)) {
            float facq[4];
#pragma unroll
            for (int r = 0; r < 4; r++) facq[r] = __shfl(fac, lg * 4 + r);
#pragma unroll
            for (int db = 0; db < 8; db++)
#pragma unroll
                for (int r = 0; r < 4; r++) acc[db][r] *= facq[r];
        }

        __builtin_amdgcn_s_setprio(1);
#pragma unroll
        for (int kk = 0; kk < 2; kk++) {
            i32x4 pf = *(const i32x4*)&pw[lr * 64 + ((kk * 4 + lg) ^ (lr & 7)) * 8];
#pragma unroll
            for (int db = 0; db < 8; db++) {
                i32x4 vf = *(const i32x4*)&Vb_[(db * 16 + lr) * 64 + ((kk * 4 + lg) ^ (lr & 7)) * 8];
                acc[db] = __builtin_amdgcn_mfma_f32_16x16x32_bf16(
                    __builtin_bit_cast(bf16x8, pf), __builtin_bit_cast(bf16x8, vf),
                    acc[db], 0, 0, 0);
            }
        }
        __builtin_amdgcn_s_setprio(0);
    }

    float inv[4];
#pragma unroll
    for (int r = 0; r < 4; r++) inv[r] = 1.0f / __shfl(l_run, lg * 4 + r);
#pragma unroll
    for (int db = 0; db < 8; db++)
#pragma unroll
        for (int r = 0; r < 4; r++) {
            int trow = q0 + w * 16 + lg * 4 + r;
            ctx[(size_t)(b * SEQ + trow) * HIDDEN + h * HDIM + db * 16 + lr] =
                f2bf(acc[db][r] * inv[r]);
        }
}

extern "C" void kernel_launch(void* const* d_in, const int* in_sizes, int n_in,
                              void* d_out, int out_size, void* d_ws, size_t ws_size,
                              hipStream_t stream)
{
    (void)in_sizes; (void)n_in; (void)out_size; (void)ws_size;
    const float* X  = (const float*)d_in[0];
    const float* Wq = (const float*)d_in[1];
    const float* Wk = (const float*)d_in[2];
    const float* Wv = (const float*)d_in[3];
    const float* Wo = (const float*)d_in[4];
    float* out = (float*)d_out;
    char* ws = (char*)d_ws;

    unsigned short* Xb  = (unsigned short*)(ws);                 // 16 MB  (4096x2048 bf16)
    unsigned short* WqT = (unsigned short*)(ws + 16777216);      // 8 MB each, N x K bf16
    unsigned short* WkT = (unsigned short*)(ws + 25165824);
    unsigned short* WvT = (unsigned short*)(ws + 33554432);
    unsigned short* WoT = (unsigned short*)(ws + 41943040);
    unsigned short* Qb  = (unsigned short*)(ws + 50331648);      // 16 MB each
    unsigned short* Kb  = (unsigned short*)(ws + 67108864);
    unsigned short* Vb  = (unsigned short*)(ws + 83886080);
    unsigned short* Vt  = (unsigned short*)(ws + 100663296);
    unsigned short* Cx  = (unsigned short*)(ws + 117440512);
    float* ctab = (float*)(ws + 134217728);                      // 0.5 MB each
    float* stab = (float*)(ws + 134742016);

    k_rope_tables<<<512, 256, 0, stream>>>(ctab, stab);
    k_cvt_bf16<<<8192, 256, 0, stream>>>(X, Xb, 2097152);
    k_transcvt<<<dim3(64, 64), dim3(32, 8), 0, stream>>>(Wq, WqT);
    k_transcvt<<<dim3(64, 64), dim3(32, 8), 0, stream>>>(Wk, WkT);
    k_transcvt<<<dim3(64, 64), dim3(32, 8), 0, stream>>>(Wv, WvT);
    k_transcvt<<<dim3(64, 64), dim3(32, 8), 0, stream>>>(Wo, WoT);
    k_gemm256<1><<<768, 512, 0, stream>>>(Xb, WqT, WkT, WvT, Qb, Kb, Vb, 2048);
    k_rope<<<dim3(16384, 2), 256, 0, stream>>>(Qb, Kb, ctab, stab);
    k_vtrans<<<dim3(4, 64, 32), dim3(32, 8), 0, stream>>>(Vb, Vt);
    k_attn<<<dim3(32, 32), 256, 0, stream>>>(Qb, Kb, Vt, Cx);
    k_gemm256<0><<<256, 512, 0, stream>>>(Cx, WoT, WoT, WoT, out, out, out, 2048);
}

// Round 8
// 331.657 us; speedup vs baseline: 1.4905x; 1.0028x over previous
//
#include <hip/hip_runtime.h>

#define HIDDEN 2048
#define SEQ    2048
#define BATCH  2
#define NHEAD  16
#define HDIM   128

typedef __attribute__((ext_vector_type(4))) int    i32x4;
typedef __attribute__((ext_vector_type(4))) float  f32x4;
typedef __attribute__((ext_vector_type(8))) __bf16 bf16x8;

__device__ __forceinline__ unsigned short f2bf(float f) {
    return __builtin_bit_cast(unsigned short, (__bf16)f);   // hw RNE cvt
}
__device__ __forceinline__ float bf2f(unsigned short h) {
    unsigned u = ((unsigned)h) << 16;
    return __builtin_bit_cast(float, u);
}
// async global->LDS, 16B per lane; dest must be wave-uniform base + lane*16
__device__ __forceinline__ void gl_lds16(const unsigned short* g, unsigned short* l) {
    __builtin_amdgcn_global_load_lds(
        (const __attribute__((address_space(1))) unsigned int*)g,
        (__attribute__((address_space(3))) unsigned int*)l, 16, 0, 0);
}

// ---------------- RoPE tables: ctab/stab[t*64 + i] = cos/sin(t * 10000^(-i/64))
__global__ void k_rope_tables(float* __restrict__ ctab, float* __restrict__ stab) {
    int idx = blockIdx.x * 256 + threadIdx.x;      // exactly SEQ*64 threads
    int t = idx >> 6, i = idx & 63;
    float inv = expf(-(float)i * 0.14391156831212793f);  // ln(10000)/64
    float ang = (float)t * inv;
    ctab[idx] = cosf(ang);
    stab[idx] = sinf(ang);
}

// ---------------- fp32 -> bf16 convert (4 elems/thread)
__global__ void k_cvt_bf16(const float* __restrict__ in, unsigned short* __restrict__ out, int n4) {
    int idx = blockIdx.x * blockDim.x + threadIdx.x;
    if (idx < n4) {
        float4 v = ((const float4*)in)[idx];
        ushort4 o;
        o.x = f2bf(v.x); o.y = f2bf(v.y); o.z = f2bf(v.z); o.w = f2bf(v.w);
        ((ushort4*)out)[idx] = o;
    }
}

// ---------------- W (K x N fp32) -> W^T (N x K bf16), 32x32 LDS tiles
__global__ void k_transcvt(const float* __restrict__ in, unsigned short* __restrict__ out) {
    __shared__ float tile[32][33];
    int tx = threadIdx.x, ty = threadIdx.y;
    int x = blockIdx.x * 32 + tx, y0 = blockIdx.y * 32;
#pragma unroll
    for (int i = 0; i < 4; i++)
        tile[ty + i * 8][tx] = in[(size_t)(y0 + ty + i * 8) * HIDDEN + x];
    __syncthreads();
    int x2 = blockIdx.y * 32 + tx, y2 = blockIdx.x * 32;
#pragma unroll
    for (int i = 0; i < 4; i++)
        out[(size_t)(y2 + ty + i * 8) * HIDDEN + x2] = f2bf(tile[tx][ty + i * 8]);
}

// ---------------- 256x128-tile bf16 GEMM, triple-buffer LDS, counted vmcnt(6)
template <int OUTB>
__global__ __launch_bounds__(512, 1) void k_gemm256(
    const unsigned short* __restrict__ A,
    const unsigned short* __restrict__ B0, const unsigned short* __restrict__ B1,
    const unsigned short* __restrict__ B2,
    void* __restrict__ C0, void* __restrict__ C1, void* __restrict__ C2,
    int K)
{
    __shared__ __align__(16) unsigned short S[3 * 24576];   // 144 KB
    const int nwg = gridDim.x;                               // 768 or 256, %8==0
    int id = blockIdx.x;
    int wg = (id & 7) * (nwg >> 3) + (id >> 3);              // XCD-aware swizzle (T1)
    const int z = wg >> 8;                                   // 16x16 blocks per z
    const int my = (wg >> 4) & 15, nx = wg & 15;
    const unsigned short* Bm = (z == 0) ? B0 : (z == 1 ? B1 : B2);
    void* Cv = (z == 0) ? C0 : (z == 1 ? C1 : C2);
    const int m0 = my * 256, n0 = nx * 128;
    const int tid = threadIdx.x, l = tid & 63, w = tid >> 6;
    const int wm = w >> 1, wn = w & 1;                       // 4 M-waves x 2 N-waves
    const int lr = l & 15, lg = l >> 4;

    const unsigned short* sg[6];
    int so[6];
#pragma unroll
    for (int j = 0; j < 4; j++) {
        int c = tid + j * 512, row = c >> 3, k8 = c & 7;
        sg[j] = A + (size_t)(m0 + row) * K + ((k8 ^ (row & 7)) * 8);
        so[j] = row * 64 + k8 * 8;
    }
#pragma unroll
    for (int j = 0; j < 2; j++) {
        int c = tid + j * 512, row = c >> 3, k8 = c & 7;
        sg[4 + j] = Bm + (size_t)(n0 + row) * K + ((k8 ^ (row & 7)) * 8);
        so[4 + j] = 16384 + row * 64 + k8 * 8;
    }

    f32x4 acc[4][4] = {};

    auto stage = [&](int t) {
        unsigned short* buf = &S[(t % 3) * 24576];
        const int ko = t * 64;
#pragma unroll
        for (int j = 0; j < 6; j++) gl_lds16(sg[j] + ko, &buf[so[j]]);
    };
    auto compute = [&](int t) {
        const unsigned short* buf = &S[(t % 3) * 24576];
        const unsigned short* bb = buf + 16384;
        const int xk0 = (lg ^ (lr & 7)) * 8, xk1 = ((4 + lg) ^ (lr & 7)) * 8;
        i32x4 af0[4], af1[4], bf0[4], bf1[4];
#pragma unroll
        for (int i = 0; i < 4; i++) {
            int R = (wm * 64 + i * 16 + lr) * 64;
            af0[i] = *(const i32x4*)&buf[R + xk0];
            af1[i] = *(const i32x4*)&buf[R + xk1];
        }
#pragma unroll
        for (int j = 0; j < 4; j++) {
            int R = (wn * 64 + j * 16 + lr) * 64;
            bf0[j] = *(const i32x4*)&bb[R + xk0];
            bf1[j] = *(const i32x4*)&bb[R + xk1];
        }
        __builtin_amdgcn_s_setprio(1);
#pragma unroll
        for (int i = 0; i < 4; i++)
#pragma unroll
            for (int j = 0; j < 4; j++)
                acc[i][j] = __builtin_amdgcn_mfma_f32_16x16x32_bf16(
                    __builtin_bit_cast(bf16x8, af0[i]),
                    __builtin_bit_cast(bf16x8, bf0[j]), acc[i][j], 0, 0, 0);
#pragma unroll
        for (int i = 0; i < 4; i++)
#pragma unroll
            for (int j = 0; j < 4; j++)
                acc[i][j] = __builtin_amdgcn_mfma_f32_16x16x32_bf16(
                    __builtin_bit_cast(bf16x8, af1[i]),
                    __builtin_bit_cast(bf16x8, bf1[j]), acc[i][j], 0, 0, 0);
        __builtin_amdgcn_s_setprio(0);
    };

    const int nt = K / 64;                 // 32
    stage(0); stage(1);                    // 12 loads in flight
    for (int t = 0; t < nt - 1; ++t) {
        asm volatile("s_waitcnt vmcnt(6)" ::: "memory");
        __builtin_amdgcn_s_barrier();
        __builtin_amdgcn_sched_barrier(0);
        if (t < nt - 2) stage(t + 2);
        compute(t);
    }
    asm volatile("s_waitcnt vmcnt(0)" ::: "memory");
    __builtin_amdgcn_s_barrier();
    __builtin_amdgcn_sched_barrier(0);
    compute(nt - 1);

#pragma unroll
    for (int i = 0; i < 4; i++)
#pragma unroll
        for (int j = 0; j < 4; j++)
#pragma unroll
            for (int r = 0; r < 4; r++) {
                int m = m0 + wm * 64 + i * 16 + lg * 4 + r;
                int n = n0 + wn * 64 + j * 16 + lr;
                float v = acc[i][j][r];
                if (OUTB) ((unsigned short*)Cv)[(size_t)m * 2048 + n] = f2bf(v);
                else      ((float*)Cv)[(size_t)m * 2048 + n] = v;
            }
}

// ---------------- RoPE in-place on Q,K; Q scaled by log2(e)/sqrt(D) (exp2-domain)
__global__ void k_rope(unsigned short* __restrict__ Q, unsigned short* __restrict__ Kb,
                       const float* __restrict__ ctab, const float* __restrict__ stab)
{
    const int tid = threadIdx.x, l = tid & 63, w = tid >> 6;
    int hr = blockIdx.x * 4 + w;                 // head-row id, one wave each
    unsigned short* X = blockIdx.y ? Kb : Q;
    float sc = blockIdx.y ? 1.0f : 0.12751743f;  // log2(e)/sqrt(128) folded into Q
    int bt = hr >> 4, h = hr & 15, t = bt & (SEQ - 1);
    size_t base = (size_t)bt * HIDDEN + h * HDIM;
    int d0 = l * 2;
    ushort2 xv = *(const ushort2*)&X[base + d0];
    float x0 = bf2f(xv.x), x1 = bf2f(xv.y);
    float prev = __shfl(x1, (l + 63) & 63);      // x[d0-1], lane0 wraps to x[127]
    int i0 = d0 & 63, i1 = (d0 + 1) & 63;
    float c0 = ctab[t * 64 + i0], s0 = stab[t * 64 + i0];
    float c1 = ctab[t * 64 + i1], s1 = stab[t * 64 + i1];
    ushort2 ov;
    ov.x = f2bf((x0 * c0 + prev * s0) * sc);
    ov.y = f2bf((x1 * c1 + x0 * s1) * sc);
    *(ushort2*)&X[base + d0] = ov;
}

// ---------------- V[bt][h*128+d] -> Vt[bh][d][t]  (per-(b,h) transpose)
__global__ void k_vtrans(const unsigned short* __restrict__ V, unsigned short* __restrict__ Vt)
{
    __shared__ unsigned short tile[32][33];
    int z = blockIdx.z;                     // bh
    int b = z >> 4, h = z & 15;
    int tx = threadIdx.x, ty = threadIdx.y;
    int d0 = blockIdx.x * 32, t0 = blockIdx.y * 32;
    const size_t ibase = (size_t)b * SEQ * HIDDEN + h * HDIM;
#pragma unroll
    for (int i = 0; i < 4; i++)
        tile[ty + i * 8][tx] = V[ibase + (size_t)(t0 + ty + i * 8) * HIDDEN + d0 + tx];
    __syncthreads();
    const size_t obase = (size_t)z * HDIM * SEQ;
#pragma unroll
    for (int i = 0; i < 4; i++)
        Vt[obase + (size_t)(d0 + ty + i * 8) * SEQ + t0 + tx] = tile[tx][ty + i * 8];
}

// ---------------- flash attention: swapped-QK^T, Plds P-staging (proven), dbuf K/V,
// XCD-grouped grid (T1): xcd owns 4 heads (4MB K/V = one L2) x 32 q-blocks.
__global__ __launch_bounds__(256) void k_attn(
    const unsigned short* __restrict__ Q, const unsigned short* __restrict__ K,
    const unsigned short* __restrict__ Vt, unsigned short* __restrict__ ctx)
{
    __shared__ __align__(16) unsigned short Klds[2][64 * 128];
    __shared__ __align__(16) unsigned short Vlds[2][128 * 64];
    __shared__ __align__(16) unsigned short Plds[4][16 * 64];
    const int tid = threadIdx.x, l = tid & 63, w = tid >> 6;
    const int lr = l & 15, lg = l >> 4;
    const int bid = blockIdx.x;                 // 1024 blocks, 1D
    const int sX = bid >> 3;
    const int bh = (bid & 7) * 4 + (sX >> 5);   // XCD (bid&7) owns heads 4k..4k+3
    const int q0 = (sX & 31) * 64;
    const int b = bh >> 4, h = bh & 15;

    const int qrow = q0 + w * 16 + lr;
    const unsigned short* qbase = Q + (size_t)(b * SEQ + qrow) * HIDDEN + h * HDIM + lg * 8;
    i32x4 qf[4];
#pragma unroll
    for (int c = 0; c < 4; c++) qf[c] = *(const i32x4*)(qbase + c * 32);

    // staging: 4 K-chunks + 4 V-chunks per thread, source pre-swizzled (rule 21)
    const unsigned short* kg[4];
    const unsigned short* vg[4];
    int kl[4], vl[4];
#pragma unroll
    for (int c = 0; c < 4; c++) {
        int cc = tid + c * 256;
        {   int row = cc >> 4, ch = cc & 15, sch = ch ^ (row & 7);
            kg[c] = K + (size_t)(b * SEQ + row) * HIDDEN + h * HDIM + sch * 8;
            kl[c] = cc * 8; }
        {   int row = cc >> 3, ch = cc & 7, sch = ch ^ (row & 7);
            vg[c] = Vt + (size_t)(bh * HDIM + row) * SEQ + sch * 8;
            vl[c] = cc * 8; }
    }

    auto stage = [&](int t, int bsel) {
        const size_t ko = (size_t)t * 64;
#pragma unroll
        for (int c = 0; c < 4; c++) {
            gl_lds16(kg[c] + ko * HIDDEN, &Klds[bsel][kl[c]]);
            gl_lds16(vg[c] + ko,          &Vlds[bsel][vl[c]]);
        }
    };

    f32x4 acc[8] = {};
    float m_run = -1e30f, l_run = 0.f;      // per-lane stats for q-row q0+w*16+lr

    stage(0, 0);
    const int nt = SEQ / 64;                // 32
    for (int t = 0; t < nt; ++t) {
        asm volatile("s_waitcnt vmcnt(0)" ::: "memory");
        __builtin_amdgcn_s_barrier();
        asm volatile("" ::: "memory");
        __builtin_amdgcn_sched_barrier(0);
        if (t + 1 < nt) stage(t + 1, (t + 1) & 1);
        const unsigned short* Kb_ = Klds[t & 1];
        const unsigned short* Vb_ = Vlds[t & 1];

        // swapped QK^T: mfma(K,Q) -> lane(lr,lg) reg r = S[q=lr][kv=ks*16+lg*4+r]
        f32x4 s[4];
        __builtin_amdgcn_s_setprio(1);
#pragma unroll
        for (int ks = 0; ks < 4; ks++) {
            s[ks] = f32x4{0.f, 0.f, 0.f, 0.f};
#pragma unroll
            for (int c = 0; c < 4; c++) {
                i32x4 kf = *(const i32x4*)&Kb_[(ks * 16 + lr) * 128 + ((c * 4 + lg) ^ (lr & 7)) * 8];
                s[ks] = __builtin_amdgcn_mfma_f32_16x16x32_bf16(
                    __builtin_bit_cast(bf16x8, kf), __builtin_bit_cast(bf16x8, qf[c]),
                    s[ks], 0, 0, 0);
            }
        }
        __builtin_amdgcn_s_setprio(0);

        // lane-local row softmax (exp2 domain; scores pre-scaled by log2e/sqrt(D))
        float mx0 = fmaxf(fmaxf(s[0][0], s[0][1]), fmaxf(s[0][2], s[0][3]));
        float mx1 = fmaxf(fmaxf(s[1][0], s[1][1]), fmaxf(s[1][2], s[1][3]));
        float mx2 = fmaxf(fmaxf(s[2][0], s[2][1]), fmaxf(s[2][2], s[2][3]));
        float mx3 = fmaxf(fmaxf(s[3][0], s[3][1]), fmaxf(s[3][2], s[3][3]));
        float pmax = fmaxf(fmaxf(mx0, mx1), fmaxf(mx2, mx3));
        pmax = fmaxf(pmax, __shfl_xor(pmax, 16));
        pmax = fmaxf(pmax, __shfl_xor(pmax, 32));
        bool need = pmax > m_run + 8.0f;         // defer-rescale (T13), P <= 2^8
        float fac = need ? __builtin_amdgcn_exp2f(m_run - pmax) : 1.0f;
        float mn = need ? pmax : m_run;
        m_run = mn;

        float p[4][4], psum = 0.f;
#pragma unroll
        for (int ks = 0; ks < 4; ks++) {
            float e0 = __builtin_amdgcn_exp2f(s[ks][0] - mn);
            float e1 = __builtin_amdgcn_exp2f(s[ks][1] - mn);
            float e2 = __builtin_amdgcn_exp2f(s[ks][2] - mn);
            float e3 = __builtin_amdgcn_exp2f(s[ks][3] - mn);
            p[ks][0] = e0; p[ks][1] = e1; p[ks][2] = e2; p[ks][3] = e3;
            psum += (e0 + e1) + (e2 + e3);
        }
        psum += __shfl_xor(psum, 16);
        psum += __shfl_xor(psum, 32);
        l_run = l_run * fac + psum;

        // P -> LDS, involution swizzle chunk' = chunk ^ (lr&7) on 8-elem chunks
        unsigned short* pw = &Plds[w][0];
#pragma unroll
        for (int ks = 0; ks < 4; ks++) {
            ushort4 pk;
            pk.x = f2bf(p[ks][0]); pk.y = f2bf(p[ks][1]);
            pk.z = f2bf(p[ks][2]); pk.w = f2bf(p[ks][3]);
            int chunk = ks * 2 + (lg >> 1);
            *(ushort4*)&pw[lr * 64 + ((chunk ^ (lr & 7)) * 8) + (lg & 1) * 4] = pk;
        }

        if (__any((int)need)) {
            float facq[4];
#pragma unroll
            for (int r = 0; r < 4; r++) facq[r] = __shfl(fac, lg * 4 + r);
#pragma unroll
            for (int db = 0; db < 8; db++)
#pragma unroll
                for (int r = 0; r < 4; r++) acc[db][r] *= facq[r];
        }

        __builtin_amdgcn_s_setprio(1);
#pragma unroll
        for (int kk = 0; kk < 2; kk++) {
            i32x4 pf = *(const i32x4*)&pw[lr * 64 + ((kk * 4 + lg) ^ (lr & 7)) * 8];
#pragma unroll
            for (int db = 0; db < 8; db++) {
                i32x4 vf = *(const i32x4*)&Vb_[(db * 16 + lr) * 64 + ((kk * 4 + lg) ^ (lr & 7)) * 8];
                acc[db] = __builtin_amdgcn_mfma_f32_16x16x32_bf16(
                    __builtin_bit_cast(bf16x8, pf), __builtin_bit_cast(bf16x8, vf),
                    acc[db], 0, 0, 0);
            }
        }
        __builtin_amdgcn_s_setprio(0);
    }

    float inv[4];
#pragma unroll
    for (int r = 0; r < 4; r++) inv[r] = 1.0f / __shfl(l_run, lg * 4 + r);
#pragma unroll
    for (int db = 0; db < 8; db++)
#pragma unroll
        for (int r = 0; r < 4; r++) {
            int trow = q0 + w * 16 + lg * 4 + r;
            ctx[(size_t)(b * SEQ + trow) * HIDDEN + h * HDIM + db * 16 + lr] =
                f2bf(acc[db][r] * inv[r]);
        }
}

extern "C" void kernel_launch(void* const* d_in, const int* in_sizes, int n_in,
                              void* d_out, int out_size, void* d_ws, size_t ws_size,
                              hipStream_t stream)
{
    (void)in_sizes; (void)n_in; (void)out_size; (void)ws_size;
    const float* X  = (const float*)d_in[0];
    const float* Wq = (const float*)d_in[1];
    const float* Wk = (const float*)d_in[2];
    const float* Wv = (const float*)d_in[3];
    const float* Wo = (const float*)d_in[4];
    float* out = (float*)d_out;
    char* ws = (char*)d_ws;

    unsigned short* Xb  = (unsigned short*)(ws);                 // 16 MB  (4096x2048 bf16)
    unsigned short* WqT = (unsigned short*)(ws + 16777216);      // 8 MB each, N x K bf16
    unsigned short* WkT = (unsigned short*)(ws + 25165824);
    unsigned short* WvT = (unsigned short*)(ws + 33554432);
    unsigned short* WoT = (unsigned short*)(ws + 41943040);
    unsigned short* Qb  = (unsigned short*)(ws + 50331648);      // 16 MB each
    unsigned short* Kb  = (unsigned short*)(ws + 67108864);
    unsigned short* Vb  = (unsigned short*)(ws + 83886080);
    unsigned short* Vt  = (unsigned short*)(ws + 100663296);
    unsigned short* Cx  = (unsigned short*)(ws + 117440512);
    float* ctab = (float*)(ws + 134217728);                      // 0.5 MB each
    float* stab = (float*)(ws + 134742016);

    k_rope_tables<<<512, 256, 0, stream>>>(ctab, stab);
    k_cvt_bf16<<<8192, 256, 0, stream>>>(X, Xb, 2097152);
    k_transcvt<<<dim3(64, 64), dim3(32, 8), 0, stream>>>(Wq, WqT);
    k_transcvt<<<dim3(64, 64), dim3(32, 8), 0, stream>>>(Wk, WkT);
    k_transcvt<<<dim3(64, 64), dim3(32, 8), 0, stream>>>(Wv, WvT);
    k_transcvt<<<dim3(64, 64), dim3(32, 8), 0, stream>>>(Wo, WoT);
    k_gemm256<1><<<768, 512, 0, stream>>>(Xb, WqT, WkT, WvT, Qb, Kb, Vb, 2048);
    k_rope<<<dim3(16384, 2), 256, 0, stream>>>(Qb, Kb, ctab, stab);
    k_vtrans<<<dim3(4, 64, 32), dim3(32, 8), 0, stream>>>(Vb, Vt);
    k_attn<<<1024, 256, 0, stream>>>(Qb, Kb, Vt, Cx);
    k_gemm256<0><<<256, 512, 0, stream>>>(Cx, WoT, WoT, WoT, out, out, out, 2048);
}

// Round 9
// 298.211 us; speedup vs baseline: 1.6577x; 1.1122x over previous
//
#include <hip/hip_runtime.h>

#define HIDDEN 2048
#define SEQ    2048
#define BATCH  2
#define NHEAD  16
#define HDIM   128

typedef __attribute__((ext_vector_type(4))) int    i32x4;
typedef __attribute__((ext_vector_type(4))) float  f32x4;
typedef __attribute__((ext_vector_type(8))) __bf16 bf16x8;

__device__ __forceinline__ unsigned short f2bf(float f) {
    return __builtin_bit_cast(unsigned short, (__bf16)f);   // hw RNE cvt
}
__device__ __forceinline__ float bf2f(unsigned short h) {
    unsigned u = ((unsigned)h) << 16;
    return __builtin_bit_cast(float, u);
}
// async global->LDS, 16B per lane; dest must be wave-uniform base + lane*16
__device__ __forceinline__ void gl_lds16(const unsigned short* g, unsigned short* l) {
    __builtin_amdgcn_global_load_lds(
        (const __attribute__((address_space(1))) unsigned int*)g,
        (__attribute__((address_space(3))) unsigned int*)l, 16, 0, 0);
}

// ---------------- RoPE tables: ctab/stab[t*64 + i] = cos/sin(t * 10000^(-i/64))
__global__ void k_rope_tables(float* __restrict__ ctab, float* __restrict__ stab) {
    int idx = blockIdx.x * 256 + threadIdx.x;      // exactly SEQ*64 threads
    int t = idx >> 6, i = idx & 63;
    float inv = expf(-(float)i * 0.14391156831212793f);  // ln(10000)/64
    float ang = (float)t * inv;
    ctab[idx] = cosf(ang);
    stab[idx] = sinf(ang);
}

// ---------------- fp32 -> bf16 convert (4 elems/thread)
__global__ void k_cvt_bf16(const float* __restrict__ in, unsigned short* __restrict__ out, int n4) {
    int idx = blockIdx.x * blockDim.x + threadIdx.x;
    if (idx < n4) {
        float4 v = ((const float4*)in)[idx];
        ushort4 o;
        o.x = f2bf(v.x); o.y = f2bf(v.y); o.z = f2bf(v.z); o.w = f2bf(v.w);
        ((ushort4*)out)[idx] = o;
    }
}

// ---------------- W (K x N fp32) -> W^T (N x K bf16), 32x32 LDS tiles
__global__ void k_transcvt(const float* __restrict__ in, unsigned short* __restrict__ out) {
    __shared__ float tile[32][33];
    int tx = threadIdx.x, ty = threadIdx.y;
    int x = blockIdx.x * 32 + tx, y0 = blockIdx.y * 32;
#pragma unroll
    for (int i = 0; i < 4; i++)
        tile[ty + i * 8][tx] = in[(size_t)(y0 + ty + i * 8) * HIDDEN + x];
    __syncthreads();
    int x2 = blockIdx.y * 32 + tx, y2 = blockIdx.x * 32;
#pragma unroll
    for (int i = 0; i < 4; i++)
        out[(size_t)(y2 + ty + i * 8) * HIDDEN + x2] = f2bf(tile[tx][ty + i * 8]);
}

// ---------------- 256x128-tile bf16 GEMM, triple-buffer LDS, counted vmcnt(6)
template <int OUTB>
__global__ __launch_bounds__(512, 1) void k_gemm256(
    const unsigned short* __restrict__ A,
    const unsigned short* __restrict__ B0, const unsigned short* __restrict__ B1,
    const unsigned short* __restrict__ B2,
    void* __restrict__ C0, void* __restrict__ C1, void* __restrict__ C2,
    int K)
{
    __shared__ __align__(16) unsigned short S[3 * 24576];   // 144 KB
    const int nwg = gridDim.x;                               // 768 or 256, %8==0
    int id = blockIdx.x;
    int wg = (id & 7) * (nwg >> 3) + (id >> 3);              // XCD-aware swizzle (T1)
    const int z = wg >> 8;                                   // 16x16 blocks per z
    const int my = (wg >> 4) & 15, nx = wg & 15;
    const unsigned short* Bm = (z == 0) ? B0 : (z == 1 ? B1 : B2);
    void* Cv = (z == 0) ? C0 : (z == 1 ? C1 : C2);
    const int m0 = my * 256, n0 = nx * 128;
    const int tid = threadIdx.x, l = tid & 63, w = tid >> 6;
    const int wm = w >> 1, wn = w & 1;                       // 4 M-waves x 2 N-waves
    const int lr = l & 15, lg = l >> 4;

    const unsigned short* sg[6];
    int so[6];
#pragma unroll
    for (int j = 0; j < 4; j++) {
        int c = tid + j * 512, row = c >> 3, k8 = c & 7;
        sg[j] = A + (size_t)(m0 + row) * K + ((k8 ^ (row & 7)) * 8);
        so[j] = row * 64 + k8 * 8;
    }
#pragma unroll
    for (int j = 0; j < 2; j++) {
        int c = tid + j * 512, row = c >> 3, k8 = c & 7;
        sg[4 + j] = Bm + (size_t)(n0 + row) * K + ((k8 ^ (row & 7)) * 8);
        so[4 + j] = 16384 + row * 64 + k8 * 8;
    }

    f32x4 acc[4][4] = {};

    auto stage = [&](int t) {
        unsigned short* buf = &S[(t % 3) * 24576];
        const int ko = t * 64;
#pragma unroll
        for (int j = 0; j < 6; j++) gl_lds16(sg[j] + ko, &buf[so[j]]);
    };
    auto compute = [&](int t) {
        const unsigned short* buf = &S[(t % 3) * 24576];
        const unsigned short* bb = buf + 16384;
        const int xk0 = (lg ^ (lr & 7)) * 8, xk1 = ((4 + lg) ^ (lr & 7)) * 8;
        i32x4 af0[4], af1[4], bf0[4], bf1[4];
#pragma unroll
        for (int i = 0; i < 4; i++) {
            int R = (wm * 64 + i * 16 + lr) * 64;
            af0[i] = *(const i32x4*)&buf[R + xk0];
            af1[i] = *(const i32x4*)&buf[R + xk1];
        }
#pragma unroll
        for (int j = 0; j < 4; j++) {
            int R = (wn * 64 + j * 16 + lr) * 64;
            bf0[j] = *(const i32x4*)&bb[R + xk0];
            bf1[j] = *(const i32x4*)&bb[R + xk1];
        }
        __builtin_amdgcn_s_setprio(1);
#pragma unroll
        for (int i = 0; i < 4; i++)
#pragma unroll
            for (int j = 0; j < 4; j++)
                acc[i][j] = __builtin_amdgcn_mfma_f32_16x16x32_bf16(
                    __builtin_bit_cast(bf16x8, af0[i]),
                    __builtin_bit_cast(bf16x8, bf0[j]), acc[i][j], 0, 0, 0);
#pragma unroll
        for (int i = 0; i < 4; i++)
#pragma unroll
            for (int j = 0; j < 4; j++)
                acc[i][j] = __builtin_amdgcn_mfma_f32_16x16x32_bf16(
                    __builtin_bit_cast(bf16x8, af1[i]),
                    __builtin_bit_cast(bf16x8, bf1[j]), acc[i][j], 0, 0, 0);
        __builtin_amdgcn_s_setprio(0);
    };

    const int nt = K / 64;                 // 32
    stage(0); stage(1);                    // 12 loads in flight
    for (int t = 0; t < nt - 1; ++t) {
        asm volatile("s_waitcnt vmcnt(6)" ::: "memory");
        __builtin_amdgcn_s_barrier();
        __builtin_amdgcn_sched_barrier(0);
        if (t < nt - 2) stage(t + 2);
        compute(t);
    }
    asm volatile("s_waitcnt vmcnt(0)" ::: "memory");
    __builtin_amdgcn_s_barrier();
    __builtin_amdgcn_sched_barrier(0);
    compute(nt - 1);

#pragma unroll
    for (int i = 0; i < 4; i++)
#pragma unroll
        for (int j = 0; j < 4; j++)
#pragma unroll
            for (int r = 0; r < 4; r++) {
                int m = m0 + wm * 64 + i * 16 + lg * 4 + r;
                int n = n0 + wn * 64 + j * 16 + lr;
                float v = acc[i][j][r];
                if (OUTB) ((unsigned short*)Cv)[(size_t)m * 2048 + n] = f2bf(v);
                else      ((float*)Cv)[(size_t)m * 2048 + n] = v;
            }
}

// ---------------- RoPE in-place on Q,K; Q scaled by log2(e)/sqrt(D) (exp2-domain)
__global__ void k_rope(unsigned short* __restrict__ Q, unsigned short* __restrict__ Kb,
                       const float* __restrict__ ctab, const float* __restrict__ stab)
{
    const int tid = threadIdx.x, l = tid & 63, w = tid >> 6;
    int hr = blockIdx.x * 4 + w;                 // head-row id, one wave each
    unsigned short* X = blockIdx.y ? Kb : Q;
    float sc = blockIdx.y ? 1.0f : 0.12751743f;  // log2(e)/sqrt(128) folded into Q
    int bt = hr >> 4, h = hr & 15, t = bt & (SEQ - 1);
    size_t base = (size_t)bt * HIDDEN + h * HDIM;
    int d0 = l * 2;
    ushort2 xv = *(const ushort2*)&X[base + d0];
    float x0 = bf2f(xv.x), x1 = bf2f(xv.y);
    float prev = __shfl(x1, (l + 63) & 63);      // x[d0-1], lane0 wraps to x[127]
    int i0 = d0 & 63, i1 = (d0 + 1) & 63;
    float c0 = ctab[t * 64 + i0], s0 = stab[t * 64 + i0];
    float c1 = ctab[t * 64 + i1], s1 = stab[t * 64 + i1];
    ushort2 ov;
    ov.x = f2bf((x0 * c0 + prev * s0) * sc);
    ov.y = f2bf((x1 * c1 + x0 * s1) * sc);
    *(ushort2*)&X[base + d0] = ov;
}

// ---------------- V[bt][h*128+d] -> Vt[bh][d][t]  (per-(b,h) transpose)
__global__ void k_vtrans(const unsigned short* __restrict__ V, unsigned short* __restrict__ Vt)
{
    __shared__ unsigned short tile[32][33];
    int z = blockIdx.z;                     // bh
    int b = z >> 4, h = z & 15;
    int tx = threadIdx.x, ty = threadIdx.y;
    int d0 = blockIdx.x * 32, t0 = blockIdx.y * 32;
    const size_t ibase = (size_t)b * SEQ * HIDDEN + h * HDIM;
#pragma unroll
    for (int i = 0; i < 4; i++)
        tile[ty + i * 8][tx] = V[ibase + (size_t)(t0 + ty + i * 8) * HIDDEN + d0 + tx];
    __syncthreads();
    const size_t obase = (size_t)z * HDIM * SEQ;
#pragma unroll
    for (int i = 0; i < 4; i++)
        Vt[obase + (size_t)(d0 + ty + i * 8) * SEQ + t0 + tx] = tile[tx][ty + i * 8];
}

// ---------------- flash attention: swapped-QK^T, 8 waves x 16 q-rows = 128 q/block,
// K/V LDS shared by 8 waves (2 blocks/CU = 16 waves/CU), dbuf pipeline,
// XCD-grouped grid: xcd owns 4 heads x 16 q-blocks.
__global__ __launch_bounds__(512) void k_attn(
    const unsigned short* __restrict__ Q, const unsigned short* __restrict__ K,
    const unsigned short* __restrict__ Vt, unsigned short* __restrict__ ctx)
{
    __shared__ __align__(16) unsigned short Klds[2][64 * 128];   // 32 KB
    __shared__ __align__(16) unsigned short Vlds[2][128 * 64];   // 32 KB
    __shared__ __align__(16) unsigned short Plds[8][16 * 64];    // 16 KB
    const int tid = threadIdx.x, l = tid & 63, w = tid >> 6;
    const int lr = l & 15, lg = l >> 4;
    const int bid = blockIdx.x;                 // 512 blocks, 1D
    const int sX = bid >> 3;                    // 0..63
    const int bh = (bid & 7) * 4 + (sX >> 4);   // XCD (bid&7) owns heads 4k..4k+3
    const int q0 = (sX & 15) * 128;
    const int b = bh >> 4, h = bh & 15;

    const int qrow = q0 + w * 16 + lr;
    const unsigned short* qbase = Q + (size_t)(b * SEQ + qrow) * HIDDEN + h * HDIM + lg * 8;
    i32x4 qf[4];
#pragma unroll
    for (int c = 0; c < 4; c++) qf[c] = *(const i32x4*)(qbase + c * 32);

    // staging: 2 K-chunks + 2 V-chunks per thread (512 threads), source pre-swizzled
    const unsigned short* kg[2];
    const unsigned short* vg[2];
    int kl[2], vl[2];
#pragma unroll
    for (int c = 0; c < 2; c++) {
        int cc = tid + c * 512;
        {   int row = cc >> 4, ch = cc & 15, sch = ch ^ (row & 7);
            kg[c] = K + (size_t)(b * SEQ + row) * HIDDEN + h * HDIM + sch * 8;
            kl[c] = cc * 8; }
        {   int row = cc >> 3, ch = cc & 7, sch = ch ^ (row & 7);
            vg[c] = Vt + (size_t)(bh * HDIM + row) * SEQ + sch * 8;
            vl[c] = cc * 8; }
    }

    auto stage = [&](int t, int bsel) {
        const size_t ko = (size_t)t * 64;
#pragma unroll
        for (int c = 0; c < 2; c++) {
            gl_lds16(kg[c] + ko * HIDDEN, &Klds[bsel][kl[c]]);
            gl_lds16(vg[c] + ko,          &Vlds[bsel][vl[c]]);
        }
    };

    f32x4 acc[8] = {};
    float m_run = -1e30f, l_run = 0.f;      // per-lane stats for q-row q0+w*16+lr

    stage(0, 0);
    const int nt = SEQ / 64;                // 32
    for (int t = 0; t < nt; ++t) {
        asm volatile("s_waitcnt vmcnt(0)" ::: "memory");
        __builtin_amdgcn_s_barrier();
        asm volatile("" ::: "memory");
        __builtin_amdgcn_sched_barrier(0);
        if (t + 1 < nt) stage(t + 1, (t + 1) & 1);
        const unsigned short* Kb_ = Klds[t & 1];
        const unsigned short* Vb_ = Vlds[t & 1];

        // swapped QK^T: mfma(K,Q) -> lane(lr,lg) reg r = S[q=lr][kv=ks*16+lg*4+r]
        f32x4 s[4];
        __builtin_amdgcn_s_setprio(1);
#pragma unroll
        for (int ks = 0; ks < 4; ks++) {
            s[ks] = f32x4{0.f, 0.f, 0.f, 0.f};
#pragma unroll
            for (int c = 0; c < 4; c++) {
                i32x4 kf = *(const i32x4*)&Kb_[(ks * 16 + lr) * 128 + ((c * 4 + lg) ^ (lr & 7)) * 8];
                s[ks] = __builtin_amdgcn_mfma_f32_16x16x32_bf16(
                    __builtin_bit_cast(bf16x8, kf), __builtin_bit_cast(bf16x8, qf[c]),
                    s[ks], 0, 0, 0);
            }
        }
        __builtin_amdgcn_s_setprio(0);

        // lane-local row softmax (exp2 domain; scores pre-scaled by log2e/sqrt(D))
        float mx0 = fmaxf(fmaxf(s[0][0], s[0][1]), fmaxf(s[0][2], s[0][3]));
        float mx1 = fmaxf(fmaxf(s[1][0], s[1][1]), fmaxf(s[1][2], s[1][3]));
        float mx2 = fmaxf(fmaxf(s[2][0], s[2][1]), fmaxf(s[2][2], s[2][3]));
        float mx3 = fmaxf(fmaxf(s[3][0], s[3][1]), fmaxf(s[3][2], s[3][3]));
        float pmax = fmaxf(fmaxf(mx0, mx1), fmaxf(mx2, mx3));
        pmax = fmaxf(pmax, __shfl_xor(pmax, 16));
        pmax = fmaxf(pmax, __shfl_xor(pmax, 32));
        bool need = pmax > m_run + 8.0f;         // defer-rescale (T13), P <= 2^8
        float fac = need ? __builtin_amdgcn_exp2f(m_run - pmax) : 1.0f;
        float mn = need ? pmax : m_run;
        m_run = mn;

        float p[4][4], psum = 0.f;
#pragma unroll
        for (int ks = 0; ks < 4; ks++) {
            float e0 = __builtin_amdgcn_exp2f(s[ks][0] - mn);
            float e1 = __builtin_amdgcn_exp2f(s[ks][1] - mn);
            float e2 = __builtin_amdgcn_exp2f(s[ks][2] - mn);
            float e3 = __builtin_amdgcn_exp2f(s[ks][3] - mn);
            p[ks][0] = e0; p[ks][1] = e1; p[ks][2] = e2; p[ks][3] = e3;
            psum += (e0 + e1) + (e2 + e3);
        }
        psum += __shfl_xor(psum, 16);
        psum += __shfl_xor(psum, 32);
        l_run = l_run * fac + psum;

        // P -> LDS, involution swizzle chunk' = chunk ^ (lr&7) on 8-elem chunks
        unsigned short* pw = &Plds[w][0];
#pragma unroll
        for (int ks = 0; ks < 4; ks++) {
            ushort4 pk;
            pk.x = f2bf(p[ks][0]); pk.y = f2bf(p[ks][1]);
            pk.z = f2bf(p[ks][2]); pk.w = f2bf(p[ks][3]);
            int chunk = ks * 2 + (lg >> 1);
            *(ushort4*)&pw[lr * 64 + ((chunk ^ (lr & 7)) * 8) + (lg & 1) * 4] = pk;
        }

        if (__any((int)need)) {
            float facq[4];
#pragma unroll
            for (int r = 0; r < 4; r++) facq[r] = __shfl(fac, lg * 4 + r);
#pragma unroll
            for (int db = 0; db < 8; db++)
#pragma unroll
                for (int r = 0; r < 4; r++) acc[db][r] *= facq[r];
        }

        __builtin_amdgcn_s_setprio(1);
#pragma unroll
        for (int kk = 0; kk < 2; kk++) {
            i32x4 pf = *(const i32x4*)&pw[lr * 64 + ((kk * 4 + lg) ^ (lr & 7)) * 8];
#pragma unroll
            for (int db = 0; db < 8; db++) {
                i32x4 vf = *(const i32x4*)&Vb_[(db * 16 + lr) * 64 + ((kk * 4 + lg) ^ (lr & 7)) * 8];
                acc[db] = __builtin_amdgcn_mfma_f32_16x16x32_bf16(
                    __builtin_bit_cast(bf16x8, pf), __builtin_bit_cast(bf16x8, vf),
                    acc[db], 0, 0, 0);
            }
        }
        __builtin_amdgcn_s_setprio(0);
    }

    float inv[4];
#pragma unroll
    for (int r = 0; r < 4; r++) inv[r] = 1.0f / __shfl(l_run, lg * 4 + r);
#pragma unroll
    for (int db = 0; db < 8; db++)
#pragma unroll
        for (int r = 0; r < 4; r++) {
            int trow = q0 + w * 16 + lg * 4 + r;
            ctx[(size_t)(b * SEQ + trow) * HIDDEN + h * HDIM + db * 16 + lr] =
                f2bf(acc[db][r] * inv[r]);
        }
}

extern "C" void kernel_launch(void* const* d_in, const int* in_sizes, int n_in,
                              void* d_out, int out_size, void* d_ws, size_t ws_size,
                              hipStream_t stream)
{
    (void)in_sizes; (void)n_in; (void)out_size; (void)ws_size;
    const float* X  = (const float*)d_in[0];
    const float* Wq = (const float*)d_in[1];
    const float* Wk = (const float*)d_in[2];
    const float* Wv = (const float*)d_in[3];
    const float* Wo = (const float*)d_in[4];
    float* out = (float*)d_out;
    char* ws = (char*)d_ws;

    unsigned short* Xb  = (unsigned short*)(ws);                 // 16 MB  (4096x2048 bf16)
    unsigned short* WqT = (unsigned short*)(ws + 16777216);      // 8 MB each, N x K bf16
    unsigned short* WkT = (unsigned short*)(ws + 25165824);
    unsigned short* WvT = (unsigned short*)(ws + 33554432);
    unsigned short* WoT = (unsigned short*)(ws + 41943040);
    unsigned short* Qb  = (unsigned short*)(ws + 50331648);      // 16 MB each
    unsigned short* Kb  = (unsigned short*)(ws + 67108864);
    unsigned short* Vb  = (unsigned short*)(ws + 83886080);
    unsigned short* Vt  = (unsigned short*)(ws + 100663296);
    unsigned short* Cx  = (unsigned short*)(ws + 117440512);
    float* ctab = (float*)(ws + 134217728);                      // 0.5 MB each
    float* stab = (float*)(ws + 134742016);

    k_rope_tables<<<512, 256, 0, stream>>>(ctab, stab);
    k_cvt_bf16<<<8192, 256, 0, stream>>>(X, Xb, 2097152);
    k_transcvt<<<dim3(64, 64), dim3(32, 8), 0, stream>>>(Wq, WqT);
    k_transcvt<<<dim3(64, 64), dim3(32, 8), 0, stream>>>(Wk, WkT);
    k_transcvt<<<dim3(64, 64), dim3(32, 8), 0, stream>>>(Wv, WvT);
    k_transcvt<<<dim3(64, 64), dim3(32, 8), 0, stream>>>(Wo, WoT);
    k_gemm256<1><<<768, 512, 0, stream>>>(Xb, WqT, WkT, WvT, Qb, Kb, Vb, 2048);
    k_rope<<<dim3(16384, 2), 256, 0, stream>>>(Qb, Kb, ctab, stab);
    k_vtrans<<<dim3(4, 64, 32), dim3(32, 8), 0, stream>>>(Vb, Vt);
    k_attn<<<512, 512, 0, stream>>>(Qb, Kb, Vt, Cx);
    k_gemm256<0><<<256, 512, 0, stream>>>(Cx, WoT, WoT, WoT, out, out, out, 2048);
}